// Round 8
// baseline (301.078 us; speedup 1.0000x reference)
//
#include <hip/hip_runtime.h>
#include <math.h>

#define BLOCK 512
#define MSTR 209   // mags row stride (f32): odd -> conflict-free lane-major reads

typedef __attribute__((ext_vector_type(8))) short short8;
typedef __attribute__((ext_vector_type(16))) float f32x16;
typedef __attribute__((ext_vector_type(8))) float f32x8;

__device__ inline unsigned short f2bf(float x) {
    unsigned u = __float_as_uint(x);
    unsigned r = u + 0x7fffu + ((u >> 16) & 1u);
    return (unsigned short)(r >> 16);
}

struct ASplit { short8 h, l; };

// split 8 f32 (by value) into hi/lo bf16 fragments — pure register code
__device__ inline ASplit splitA(f32x8 v) {
    unsigned ah[4], al[4];
    #pragma unroll
    for (int q = 0; q < 4; ++q) {
        unsigned short h0 = f2bf(v[2*q]),   h1 = f2bf(v[2*q+1]);
        float hf0 = __uint_as_float((unsigned)h0 << 16);
        float hf1 = __uint_as_float((unsigned)h1 << 16);
        unsigned short l0 = f2bf(v[2*q] - hf0), l1 = f2bf(v[2*q+1] - hf1);
        ah[q] = (unsigned)h0 | ((unsigned)h1 << 16);
        al[q] = (unsigned)l0 | ((unsigned)l1 << 16);
    }
    ASplit r;
    r.h = __builtin_bit_cast(short8, *(uint4*)ah);
    r.l = __builtin_bit_cast(short8, *(uint4*)al);
    return r;
}

// load 8 consecutive floats at absolute padded offset i0; reflect on edges
__device__ inline f32x8 loadA8(const float* __restrict__ x, int i0) {
    f32x8 r;
    if (i0 >= 0 && i0 <= 15992) {
        float4 a0 = *(const float4*)(x + i0);
        float4 a1 = *(const float4*)(x + i0 + 4);
        r[0] = a0.x; r[1] = a0.y; r[2] = a0.z; r[3] = a0.w;
        r[4] = a1.x; r[5] = a1.y; r[6] = a1.z; r[7] = a1.w;
    } else {
        #pragma unroll
        for (int e = 0; e < 8; ++e) {
            int p = i0 + e;
            p = (p < 0) ? -p : p;
            p = (p > 15999) ? (31998 - p) : p;
            r[e] = x[p];
        }
    }
    return r;
}

// ---------------------------------------------------------------------------
// Kernel 1: filters output (64 x 201) -> tail of d_out. Mirrors _get_filters.
// ---------------------------------------------------------------------------
__global__ void fse_filters(const float* __restrict__ low_hz_,
                            const float* __restrict__ band_hz_,
                            float* __restrict__ out)
{
    int idx = blockIdx.x * 256 + threadIdx.x;
    if (idx >= 64 * 201) return;
    int c = idx / 201;
    int k = idx - c * 201;
    float lo = 50.0f + fabsf(low_hz_[c]);
    float hi = lo + 50.0f + fabsf(band_hz_[c]);
    hi = fminf(fmaxf(hi, 50.0f), 8000.0f);
    float ctr = 0.5f * (lo + hi);
    float hbw = 0.5f * (hi - lo);
    float fq = 40.0f * (float)k;
    float resp = 1.0f - fabsf(fq - ctr) / hbw;
    out[idx] = (fq >= lo && fq <= hi) ? resp : 0.0f;
}

// ---------------------------------------------------------------------------
// Kernel 1b: B in chunk-linear layout: Bt[kc][pl][part][row][8] bf16 (hi/lo).
//   row j: j<=200 -> re bin j ; 224<=j<=424 -> im bin j-224 ; else 0.
// ---------------------------------------------------------------------------
__global__ void fse_setup_B(unsigned short* __restrict__ bt)
{
    int idx = blockIdx.x * 256 + threadIdx.x;   // 13*2*4*448*8 = 372736
    if (idx >= 372736) return;
    int e   = idx & 7;
    int t   = idx >> 3;
    int row = t % 448;
    int q   = t / 448;          // ((kc*2 + pl)*4 + p)
    int p   = q & 3;
    int pl  = (q >> 2) & 1;
    int kc  = q >> 3;
    int n   = kc * 32 + p * 8 + e;
    float v = 0.0f;
    if (n < 400) {
        int bin = -1, isim = 0;
        if (row <= 200) bin = row;
        else if (row >= 224 && row <= 424) { bin = row - 224; isim = 1; }
        if (bin >= 0) {
            int a = (bin * n) % 400;            // exact integer phase reduction
            float th = 6.283185307179586f * ((float)a / 400.0f);
            float sn, cs;
            sincosf(th, &sn, &cs);
            float wn = 0.5f - 0.5f * cosf(6.283185307179586f * ((float)n / 400.0f));
            v = isim ? (-wn * sn) : (wn * cs);
        }
    }
    unsigned short h = f2bf(v);
    float hf = __uint_as_float((unsigned)h << 16);
    unsigned short l = f2bf(v - hf);
    bt[idx] = pl ? l : h;
}

// ---------------------------------------------------------------------------
// Kernel 2 (MFMA path): one block per batch item.
//  C[128 x 448] = A[128 x 416] x B[416 x 448], split-2 bf16 (3 products).
//  R8: double-buffered LDS B staged via global_load_lds (no VGPR round-trip,
//  no ds_writes), 2m x 4n wave mapping (per-wave B reads <=16 b128/kc, half
//  of R6), A per-lane from global split in-register, ONE barrier per kc.
//  C layout (HW-verified m74): col = lane&31, row = (r&3)+8*(r>>2)+4*(lane>>5).
// ---------------------------------------------------------------------------
__global__ __launch_bounds__(512, 2)
void fse_main_mfma(const float* __restrict__ wav,
                   const float* __restrict__ low_hz_,
                   const float* __restrict__ band_hz_,
                   const float* __restrict__ ln_w,
                   const float* __restrict__ ln_b,
                   const unsigned short* __restrict__ Bt,
                   float* __restrict__ out)
{
    // GEMM phase: [0,57344) buf0 | [57344,114688) buf1
    // post phase: [0,84436) mags[101][209] f32 | [84544,110400) fbuf[64*101]
    __shared__ __align__(16) char smem[114688];
    float* mags = (float*)smem;
    float* fbuf = (float*)(smem + 84544);

    __shared__ float fctr[64], finv[64];
    __shared__ int   fks[64], fke[64];
    __shared__ float red[16];
    __shared__ float stats[2];

    const int b    = blockIdx.x;
    const int tid  = threadIdx.x;
    const int w    = tid >> 6;
    const int lane = tid & 63;
    const float* __restrict__ x = wav + b * 16000;

    // ---- per-channel filter params
    if (tid < 64) {
        float lo = 50.0f + fabsf(low_hz_[tid]);
        float hi = lo + 50.0f + fabsf(band_hz_[tid]);
        hi = fminf(fmaxf(hi, 50.0f), 8000.0f);
        float ctr = 0.5f * (lo + hi);
        float hbw = 0.5f * (hi - lo);
        int ks = (int)ceilf(lo * 0.025f);
        if (ks < 0) ks = 0;
        while (40.0f * (float)ks < lo) ++ks;
        while (ks > 0 && 40.0f * (float)(ks - 1) >= lo) --ks;
        int ke = (int)floorf(hi * 0.025f);
        if (ke > 200) ke = 200;
        while (40.0f * (float)ke > hi) --ke;
        while (ke < 200 && 40.0f * (float)(ke + 1) <= hi) ++ke;
        fctr[tid] = ctr;
        finv[tid] = (hbw > 0.0f) ? (1.0f / hbw) : 0.0f;
        fks[tid]  = ks;
        fke[tid]  = ke;
    }

    const int mg    = w >> 2;          // m-group: rows 64*mg .. 64*mg+63
    const int nq    = w & 3;           // n-group
    const int nbase = (nq < 3) ? nq * 4 : 11;   // {0,4,8,11}
    const int cnt   = (nq < 2) ? 4 : 3;         // {4,4,3,3} -> nt 0..13
    const int jrow  = lane & 31;
    const int g     = lane >> 5;

    const int arow0 = 64 * mg + jrow;
    const int arow1 = 64 * mg + 32 + jrow;
    const int te0   = (arow0 <= 100) ? arow0 : 50;
    const int te1   = (arow1 <= 100) ? arow1 : 50;
    const int ab0   = 160 * te0 - 200 + g * 8;
    const int ab1   = 160 * te1 - 200 + g * 8;

    const uint4* __restrict__ btg = (const uint4*)Bt;   // 3584 uint4 per kc

    // ---- prologue: DMA B(0) into buffer 0 (wave-uniform LDS dest, per-lane src)
    {
        const uint4* src = btg + (w << 6) + lane;
        char* dstb = smem + ((w << 6) * 16);
        #pragma unroll
        for (int i = 0; i < 7; ++i) {
            __builtin_amdgcn_global_load_lds(
                (const __attribute__((address_space(1))) unsigned*)(src + i * 512),
                (__attribute__((address_space(3))) unsigned*)(dstb + i * 8192),
                16, 0, 0);
        }
    }
    __syncthreads();

    f32x16 accA[4], accB[4];           // [n] for m-tile 0 / 1
    #pragma unroll
    for (int n = 0; n < 4; ++n) {
        #pragma unroll
        for (int e = 0; e < 16; ++e) { accA[n][e] = 0.0f; accB[n][e] = 0.0f; }
    }

    int curoff = 0;
    for (int kc = 0; kc < 13; ++kc) {
        // A loads FIRST (consumed this kc: their wait leaves DMA in flight)
        f32x8 a00 = loadA8(x, ab0 + kc * 32);
        f32x8 a01 = loadA8(x, ab0 + kc * 32 + 16);
        f32x8 a10 = loadA8(x, ab1 + kc * 32);
        f32x8 a11 = loadA8(x, ab1 + kc * 32 + 16);

        // B(kc+1) DMA into the other buffer (written only after the barrier
        // that ended kc-1, read only after the barrier ending this kc)
        if (kc < 12) {
            const uint4* src = btg + (kc + 1) * 3584 + (w << 6) + lane;
            char* dstb = smem + (curoff ^ 57344) + ((w << 6) * 16);
            #pragma unroll
            for (int i = 0; i < 7; ++i) {
                __builtin_amdgcn_global_load_lds(
                    (const __attribute__((address_space(1))) unsigned*)(src + i * 512),
                    (__attribute__((address_space(3))) unsigned*)(dstb + i * 8192),
                    16, 0, 0);
            }
        }

        ASplit A00 = splitA(a00);   // mt0, s0
        ASplit A01 = splitA(a01);   // mt0, s1
        ASplit A10 = splitA(a10);   // mt1, s0
        ASplit A11 = splitA(a11);   // mt1, s1

        const unsigned short* bs = (const unsigned short*)(smem + curoff);
        #pragma unroll
        for (int s = 0; s < 2; ++s) {
            const short8 Ah0 = s ? A01.h : A00.h;
            const short8 Al0 = s ? A01.l : A00.l;
            const short8 Ah1 = s ? A11.h : A10.h;
            const short8 Al1 = s ? A11.l : A10.l;
            const int part = s * 2 + g;
            const int bhof = part * 3584;          // [pl=0][part] base (shorts)
            const int blof = (4 + part) * 3584;    // [pl=1][part]
            #pragma unroll
            for (int n = 0; n < 4; ++n) {
                if (n < cnt) {
                    const int ro = (nbase + n) * 32 + jrow;
                    short8 Bh = *(const short8*)(bs + bhof + ro * 8);
                    short8 Bl = *(const short8*)(bs + blof + ro * 8);
                    accA[n] = __builtin_amdgcn_mfma_f32_32x32x16_bf16(Ah0, Bh, accA[n], 0, 0, 0);
                    accA[n] = __builtin_amdgcn_mfma_f32_32x32x16_bf16(Ah0, Bl, accA[n], 0, 0, 0);
                    accA[n] = __builtin_amdgcn_mfma_f32_32x32x16_bf16(Al0, Bh, accA[n], 0, 0, 0);
                    accB[n] = __builtin_amdgcn_mfma_f32_32x32x16_bf16(Ah1, Bh, accB[n], 0, 0, 0);
                    accB[n] = __builtin_amdgcn_mfma_f32_32x32x16_bf16(Ah1, Bl, accB[n], 0, 0, 0);
                    accB[n] = __builtin_amdgcn_mfma_f32_32x32x16_bf16(Al1, Bh, accB[n], 0, 0, 0);
                }
            }
        }

        __syncthreads();    // compiler drains vmcnt(0): DMA complete, reads done
        curoff ^= 57344;
    }

    // ---- epilogue phase 1: write all RE tiles (nt < 7) to mags
    #pragma unroll
    for (int n = 0; n < 4; ++n) {
        if (n < cnt) {
            const int nt = nbase + n;
            if (nt < 7) {
                const int k = nt * 32 + jrow;
                if (k <= 200) {
                    #pragma unroll
                    for (int r = 0; r < 16; ++r) {
                        int t = 64 * mg + (r & 3) + 8 * (r >> 2) + 4 * g;
                        if (t <= 100)      mags[t * MSTR + k]        = accA[n][r];
                        if (t + 32 <= 100) mags[(t + 32) * MSTR + k] = accB[n][r];
                    }
                }
            }
        }
    }
    __syncthreads();
    // ---- epilogue phase 2: fold IM tiles (nt >= 7) into magnitude
    #pragma unroll
    for (int n = 0; n < 4; ++n) {
        if (n < cnt) {
            const int nt = nbase + n;
            if (nt >= 7 && nt < 14) {
                const int k = (nt - 7) * 32 + jrow;
                if (k <= 200) {
                    #pragma unroll
                    for (int r = 0; r < 16; ++r) {
                        int t = 64 * mg + (r & 3) + 8 * (r >> 2) + 4 * g;
                        if (t <= 100) {
                            float re = mags[t * MSTR + k];
                            float im = accA[n][r];
                            mags[t * MSTR + k] = sqrtf(re * re + im * im);
                        }
                        if (t + 32 <= 100) {
                            float re = mags[(t + 32) * MSTR + k];
                            float im = accB[n][r];
                            mags[(t + 32) * MSTR + k] = sqrtf(re * re + im * im);
                        }
                    }
                }
            }
        }
    }
    __syncthreads();

    // ---- filterbank: lane = t (wave-uniform k-loop, conflict-free reads)
    {
        const int t0 = lane;
        const int t1v = 64 + lane;
        const int t1 = (t1v <= 100) ? t1v : 100;   // clamped read, guarded store
        #pragma unroll
        for (int i = 0; i < 8; ++i) {
            const int c = w * 8 + i;
            const float ctr = fctr[c];
            const float inv = finv[c];
            const int ks = fks[c], ke = fke[c];
            float a0 = 0.0f, a1 = 0.0f;
            for (int k = ks; k <= ke; ++k) {
                float resp = 1.0f - fabsf(40.0f * (float)k - ctr) * inv;
                a0 = fmaf(resp, mags[t0 * MSTR + k], a0);
                a1 = fmaf(resp, mags[t1 * MSTR + k], a1);
            }
            fbuf[c * 101 + t0] = a0;
            if (t1v <= 100) fbuf[c * 101 + t1v] = a1;
        }
    }
    __syncthreads();

    // ---- global LayerNorm (one-pass: sum + sumsq)
    float s = 0.0f, ss = 0.0f;
    for (int i = tid; i < 6464; i += BLOCK) {
        float vv = fbuf[i];
        s += vv;
        ss = fmaf(vv, vv, ss);
    }
    #pragma unroll
    for (int off = 32; off > 0; off >>= 1) {
        s  += __shfl_down(s,  off, 64);
        ss += __shfl_down(ss, off, 64);
    }
    if (lane == 0) { red[w] = s; red[8 + w] = ss; }
    __syncthreads();
    if (tid == 0) {
        float ts = 0.0f, tss = 0.0f;
        for (int i = 0; i < 8; ++i) { ts += red[i]; tss += red[8 + i]; }
        float mu = ts * (1.0f / 6464.0f);
        stats[0] = mu;
        stats[1] = tss * (1.0f / 6464.0f) - mu * mu;
    }
    __syncthreads();
    const float mu   = stats[0];
    const float isig = 1.0f / sqrtf(stats[1] + 1e-5f);

    // ---- log-energy + interp 101->64 + transposed store
    for (int idx = tid; idx < 4096; idx += BLOCK) {
        const int to = idx >> 6;
        const int c  = idx & 63;
        float pos = ((float)to + 0.5f) * 1.578125f - 0.5f;
        pos = fminf(fmaxf(pos, 0.0f), 100.0f);
        int i0 = (int)floorf(pos);
        int i1 = i0 + 1; if (i1 > 100) i1 = 100;
        float fr = pos - (float)i0;
        float wc = ln_w[c], bc = ln_b[c];
        float x0 = fbuf[c * 101 + i0];
        float x1 = fbuf[c * 101 + i1];
        float y0 = fmaf(wc, (x0 - mu) * isig, bc);
        float y1 = fmaf(wc, (x1 - mu) * isig, bc);
        float l0 = log10f(fmaf(y0, y0, 1e-6f));
        float l1 = log10f(fmaf(y1, y1, 1e-6f));
        out[b * 4096 + idx] = l0 * (1.0f - fr) + l1 * fr;
    }
}

// ---------------------------------------------------------------------------
// Fallback (R2 VALU path) if ws_size is too small for the B table.
// ---------------------------------------------------------------------------
__global__ __launch_bounds__(512, 2)
void fse_main_valu(const float* __restrict__ wav,
                   const float* __restrict__ low_hz_,
                   const float* __restrict__ band_hz_,
                   const float* __restrict__ ln_w,
                   const float* __restrict__ ln_b,
                   float* __restrict__ out)
{
    __shared__ float  xp[16400];
    __shared__ float2 Xs[8][204];
    __shared__ float  mags[8][204];
    __shared__ float  fbuf[64 * 101];
    __shared__ float  fctr[64], finv[64];
    __shared__ int    fks[64], fke[64];
    __shared__ float  red[8];
    __shared__ float  stats[2];

    const int b    = blockIdx.x;
    const int tid  = threadIdx.x;
    const int w    = tid >> 6;
    const int lane = tid & 63;
    const float* __restrict__ x = wav + b * 16000;

    for (int i = tid; i < 16400; i += BLOCK) {
        int p = i - 200;
        p = (p < 0) ? -p : p;
        p = (p > 15999) ? (31998 - p) : p;
        xp[i] = x[p];
    }
    if (tid < 64) {
        float lo = 50.0f + fabsf(low_hz_[tid]);
        float hi = lo + 50.0f + fabsf(band_hz_[tid]);
        hi = fminf(fmaxf(hi, 50.0f), 8000.0f);
        float ctr = 0.5f * (lo + hi);
        float hbw = 0.5f * (hi - lo);
        int ks = (int)ceilf(lo * 0.025f);
        if (ks < 0) ks = 0;
        while (40.0f * (float)ks < lo) ++ks;
        while (ks > 0 && 40.0f * (float)(ks - 1) >= lo) --ks;
        int ke = (int)floorf(hi * 0.025f);
        if (ke > 200) ke = 200;
        while (40.0f * (float)ke > hi) --ke;
        while (ke < 200 && 40.0f * (float)(ke + 1) <= hi) ++ke;
        fctr[tid] = ctr;
        finv[tid] = (hbw > 0.0f) ? (1.0f / hbw) : 0.0f;
        fks[tid]  = ks;
        fke[tid]  = ke;
    }
    __syncthreads();

    const float cctr = fctr[lane];
    const float cinv = finv[lane];
    const int   cks  = fks[lane];
    const int   cke  = fke[lane];

    float reX[4][13], imX[4][13];
    const float2* __restrict__ xp2 = (const float2*)xp;
    float c0[4], s0[4], c1[4], s1[4], cd[4], sd[4];
    #pragma unroll
    for (int m = 0; m < 4; ++m) {
        const int k = m * 64 + lane;
        const float th = -0.015707963267948966f * (float)k;
        sincosf(th, &s1[m], &c1[m]);
        sincosf(th + th, &sd[m], &cd[m]);
        c0[m] = 1.0f; s0[m] = 0.0f;
        #pragma unroll
        for (int j = 0; j < 13; ++j) { reX[m][j] = 0.0f; imX[m][j] = 0.0f; }
    }
    const int o12 = (w < 5) ? 640 * 12 : 0;
    int ib = 80 * w;
    #pragma unroll 2
    for (int h = 0; h < 200; ++h) {
        #pragma unroll
        for (int j = 0; j < 13; ++j) {
            const int off = (j == 12) ? o12 : 640 * j;
            float2 f = xp2[ib + off];
            #pragma unroll
            for (int m = 0; m < 4; ++m) {
                reX[m][j] = fmaf(f.x, c0[m], reX[m][j]);
                imX[m][j] = fmaf(f.x, s0[m], imX[m][j]);
                reX[m][j] = fmaf(f.y, c1[m], reX[m][j]);
                imX[m][j] = fmaf(f.y, s1[m], imX[m][j]);
            }
        }
        #pragma unroll
        for (int m = 0; m < 4; ++m) {
            float nc0 = fmaf(c0[m], cd[m], -(s0[m] * sd[m]));
            float ns0 = fmaf(s0[m], cd[m],  (c0[m] * sd[m]));
            float nc1 = fmaf(c1[m], cd[m], -(s1[m] * sd[m]));
            float ns1 = fmaf(s1[m], cd[m],  (c1[m] * sd[m]));
            c0[m] = nc0; s0[m] = ns0; c1[m] = nc1; s1[m] = ns1;
        }
        ++ib;
    }

    float2* __restrict__ myX   = &Xs[w][0];
    float*  __restrict__ mymag = &mags[w][0];
    for (int j = 0; j < 13; ++j) {
        const int t = w + 8 * j;
        if (t > 100) break;
        #pragma unroll
        for (int m = 0; m < 4; ++m) {
            const int k = m * 64 + lane;
            if (k < 202) myX[k] = make_float2(reX[m][j], imX[m][j]);
        }
        asm volatile("s_waitcnt lgkmcnt(0)" ::: "memory");
        #pragma unroll
        for (int m = 0; m < 4; ++m) {
            const int k = m * 64 + lane;
            if (k <= 200) {
                float2 xm = (k == 0) ? myX[1] : myX[k - 1];
                float imm = (k == 0) ? -xm.y : xm.y;
                float2 xq = myX[k + 1];
                float rw = 0.5f * reX[m][j] - 0.25f * (xm.x + xq.x);
                float iw = 0.5f * imX[m][j] - 0.25f * (imm  + xq.y);
                mymag[k] = sqrtf(rw * rw + iw * iw);
            }
        }
        asm volatile("s_waitcnt lgkmcnt(0)" ::: "memory");
        float acc = 0.0f;
        for (int k = cks; k <= cke; ++k) {
            float resp = 1.0f - fabsf(40.0f * (float)k - cctr) * cinv;
            acc = fmaf(resp, mymag[k], acc);
        }
        fbuf[lane * 101 + t] = acc;
    }
    __syncthreads();

    float s = 0.0f;
    for (int i = tid; i < 6464; i += BLOCK) s += fbuf[i];
    #pragma unroll
    for (int off = 32; off > 0; off >>= 1) s += __shfl_down(s, off, 64);
    if (lane == 0) red[w] = s;
    __syncthreads();
    if (tid == 0) {
        float tsum = 0.0f;
        for (int i = 0; i < 8; ++i) tsum += red[i];
        stats[0] = tsum * (1.0f / 6464.0f);
    }
    __syncthreads();
    const float mu = stats[0];
    float v = 0.0f;
    for (int i = tid; i < 6464; i += BLOCK) { float d = fbuf[i] - mu; v = fmaf(d, d, v); }
    #pragma unroll
    for (int off = 32; off > 0; off >>= 1) v += __shfl_down(v, off, 64);
    if (lane == 0) red[w] = v;
    __syncthreads();
    if (tid == 0) {
        float tsum = 0.0f;
        for (int i = 0; i < 8; ++i) tsum += red[i];
        stats[1] = tsum * (1.0f / 6464.0f);
    }
    __syncthreads();
    const float var  = stats[1];
    const float isig = 1.0f / sqrtf(var + 1e-5f);

    for (int idx = tid; idx < 4096; idx += BLOCK) {
        const int to = idx >> 6;
        const int c  = idx & 63;
        float pos = ((float)to + 0.5f) * 1.578125f - 0.5f;
        pos = fminf(fmaxf(pos, 0.0f), 100.0f);
        int i0 = (int)floorf(pos);
        int i1 = i0 + 1; if (i1 > 100) i1 = 100;
        float fr = pos - (float)i0;
        float wc = ln_w[c], bc = ln_b[c];
        float x0 = fbuf[c * 101 + i0];
        float x1 = fbuf[c * 101 + i1];
        float y0 = fmaf(wc, (x0 - mu) * isig, bc);
        float y1 = fmaf(wc, (x1 - mu) * isig, bc);
        float l0 = log10f(fmaf(y0, y0, 1e-6f));
        float l1 = log10f(fmaf(y1, y1, 1e-6f));
        out[b * 4096 + idx] = l0 * (1.0f - fr) + l1 * fr;
    }
}

extern "C" void kernel_launch(void* const* d_in, const int* in_sizes, int n_in,
                              void* d_out, int out_size, void* d_ws, size_t ws_size,
                              hipStream_t stream)
{
    const float* wav = (const float*)d_in[0];
    const float* lo  = (const float*)d_in[1];
    const float* bd  = (const float*)d_in[2];
    const float* lw  = (const float*)d_in[3];
    const float* lb  = (const float*)d_in[4];
    float* out = (float*)d_out;

    fse_filters<<<(64 * 201 + 255) / 256, 256, 0, stream>>>(lo, bd, out + 1024 * 4096);

    const size_t BNEED = (size_t)372736 * sizeof(unsigned short); // 745472 B
    if (ws_size >= BNEED) {
        unsigned short* Bts = (unsigned short*)d_ws;
        fse_setup_B<<<(372736 + 255) / 256, 256, 0, stream>>>(Bts);
        fse_main_mfma<<<1024, BLOCK, 0, stream>>>(wav, lo, bd, lw, lb, Bts, out);
    } else {
        fse_main_valu<<<1024, BLOCK, 0, stream>>>(wav, lo, bd, lw, lb, out);
    }
}

// Round 9
// 260.373 us; speedup vs baseline: 1.1563x; 1.1563x over previous
//
#include <hip/hip_runtime.h>
#include <math.h>

#define BLOCK 512
#define MSTR 209   // mags row stride (f32): odd -> conflict-free lane-major reads

typedef __attribute__((ext_vector_type(8))) short short8;
typedef __attribute__((ext_vector_type(16))) float f32x16;
typedef __attribute__((ext_vector_type(8))) float f32x8;

__device__ inline unsigned short f2bf(float x) {
    unsigned u = __float_as_uint(x);
    unsigned r = u + 0x7fffu + ((u >> 16) & 1u);
    return (unsigned short)(r >> 16);
}

struct ASplit { short8 h, l; };

// split 8 f32 (by value) into hi/lo bf16 fragments — pure register code
__device__ inline ASplit splitA(f32x8 v) {
    unsigned ah[4], al[4];
    #pragma unroll
    for (int q = 0; q < 4; ++q) {
        unsigned short h0 = f2bf(v[2*q]),   h1 = f2bf(v[2*q+1]);
        float hf0 = __uint_as_float((unsigned)h0 << 16);
        float hf1 = __uint_as_float((unsigned)h1 << 16);
        unsigned short l0 = f2bf(v[2*q] - hf0), l1 = f2bf(v[2*q+1] - hf1);
        ah[q] = (unsigned)h0 | ((unsigned)h1 << 16);
        al[q] = (unsigned)l0 | ((unsigned)l1 << 16);
    }
    ASplit r;
    r.h = __builtin_bit_cast(short8, *(uint4*)ah);
    r.l = __builtin_bit_cast(short8, *(uint4*)al);
    return r;
}

// load 8 consecutive floats at absolute padded offset i0; reflect on edges
__device__ inline f32x8 loadA8(const float* __restrict__ x, int i0) {
    f32x8 r;
    if (i0 >= 0 && i0 <= 15992) {
        float4 a0 = *(const float4*)(x + i0);
        float4 a1 = *(const float4*)(x + i0 + 4);
        r[0] = a0.x; r[1] = a0.y; r[2] = a0.z; r[3] = a0.w;
        r[4] = a1.x; r[5] = a1.y; r[6] = a1.z; r[7] = a1.w;
    } else {
        #pragma unroll
        for (int e = 0; e < 8; ++e) {
            int p = i0 + e;
            p = (p < 0) ? -p : p;
            p = (p > 15999) ? (31998 - p) : p;
            r[e] = x[p];
        }
    }
    return r;
}

// ---------------------------------------------------------------------------
// Kernel 1: filters output (64 x 201) -> tail of d_out. Mirrors _get_filters.
// ---------------------------------------------------------------------------
__global__ void fse_filters(const float* __restrict__ low_hz_,
                            const float* __restrict__ band_hz_,
                            float* __restrict__ out)
{
    int idx = blockIdx.x * 256 + threadIdx.x;
    if (idx >= 64 * 201) return;
    int c = idx / 201;
    int k = idx - c * 201;
    float lo = 50.0f + fabsf(low_hz_[c]);
    float hi = lo + 50.0f + fabsf(band_hz_[c]);
    hi = fminf(fmaxf(hi, 50.0f), 8000.0f);
    float ctr = 0.5f * (lo + hi);
    float hbw = 0.5f * (hi - lo);
    float fq = 40.0f * (float)k;
    float resp = 1.0f - fabsf(fq - ctr) / hbw;
    out[idx] = (fq >= lo && fq <= hi) ? resp : 0.0f;
}

// ---------------------------------------------------------------------------
// Kernel 1b: B in chunk-linear layout: Bt[kc][pl][part][row][8] bf16 (hi/lo).
//   row j: j<=200 -> re bin j ; 224<=j<=424 -> im bin j-224 ; else 0.
// ---------------------------------------------------------------------------
__global__ void fse_setup_B(unsigned short* __restrict__ bt)
{
    int idx = blockIdx.x * 256 + threadIdx.x;   // 13*2*4*448*8 = 372736
    if (idx >= 372736) return;
    int e   = idx & 7;
    int t   = idx >> 3;
    int row = t % 448;
    int q   = t / 448;          // ((kc*2 + pl)*4 + p)
    int p   = q & 3;
    int pl  = (q >> 2) & 1;
    int kc  = q >> 3;
    int n   = kc * 32 + p * 8 + e;
    float v = 0.0f;
    if (n < 400) {
        int bin = -1, isim = 0;
        if (row <= 200) bin = row;
        else if (row >= 224 && row <= 424) { bin = row - 224; isim = 1; }
        if (bin >= 0) {
            int a = (bin * n) % 400;            // exact integer phase reduction
            float th = 6.283185307179586f * ((float)a / 400.0f);
            float sn, cs;
            sincosf(th, &sn, &cs);
            float wn = 0.5f - 0.5f * cosf(6.283185307179586f * ((float)n / 400.0f));
            v = isim ? (-wn * sn) : (wn * cs);
        }
    }
    unsigned short h = f2bf(v);
    float hf = __uint_as_float((unsigned)h << 16);
    unsigned short l = f2bf(v - hf);
    bt[idx] = pl ? l : h;
}

// ---------------------------------------------------------------------------
// Kernel 2 (MFMA path): one block per batch item.
//  C[128 x 448] = A[128 x 416] x B[416 x 448], split-2 bf16 (3 products).
//  R9 = R6 proven schedule (reg-staged B dbuf, A one-kc-ahead, 1 barrier/kc)
//  with 2m x 4pair wave mapping: each wave owns (re,im) tile PAIRS of the
//  same bins -> B frag reads 224->112 per kc (LDS wall halves) and magnitude
//  is computed fully in-register (no 2-phase mags epilogue).
//  C layout (HW-verified m74): col = lane&31, row = (r&3)+8*(r>>2)+4*(lane>>5).
// ---------------------------------------------------------------------------
__global__ __launch_bounds__(512, 2)
void fse_main_mfma(const float* __restrict__ wav,
                   const float* __restrict__ low_hz_,
                   const float* __restrict__ band_hz_,
                   const float* __restrict__ ln_w,
                   const float* __restrict__ ln_b,
                   const unsigned short* __restrict__ Bt,
                   float* __restrict__ out)
{
    // GEMM phase: [0,57344) buf0 | [57344,114688) buf1
    // post phase: [0,84436) mags[101][209] f32 | [84544,110400) fbuf[64*101]
    __shared__ __align__(16) char smem[114688];
    float* mags = (float*)smem;
    float* fbuf = (float*)(smem + 84544);

    __shared__ float fctr[64], finv[64];
    __shared__ int   fks[64], fke[64];
    __shared__ float red[16];
    __shared__ float stats[2];

    const int b    = blockIdx.x;
    const int tid  = threadIdx.x;
    const int w    = tid >> 6;
    const int lane = tid & 63;
    const float* __restrict__ x = wav + b * 16000;

    // ---- per-channel filter params
    if (tid < 64) {
        float lo = 50.0f + fabsf(low_hz_[tid]);
        float hi = lo + 50.0f + fabsf(band_hz_[tid]);
        hi = fminf(fmaxf(hi, 50.0f), 8000.0f);
        float ctr = 0.5f * (lo + hi);
        float hbw = 0.5f * (hi - lo);
        int ks = (int)ceilf(lo * 0.025f);
        if (ks < 0) ks = 0;
        while (40.0f * (float)ks < lo) ++ks;
        while (ks > 0 && 40.0f * (float)(ks - 1) >= lo) --ks;
        int ke = (int)floorf(hi * 0.025f);
        if (ke > 200) ke = 200;
        while (40.0f * (float)ke > hi) --ke;
        while (ke < 200 && 40.0f * (float)(ke + 1) <= hi) ++ke;
        fctr[tid] = ctr;
        finv[tid] = (hbw > 0.0f) ? (1.0f / hbw) : 0.0f;
        fks[tid]  = ks;
        fke[tid]  = ke;
    }

    const int mg    = w >> 2;          // m-group: rows 64*mg .. 64*mg+63
    const int pq    = w & 3;           // pair-group
    const int pbase = pq * 2;          // pairs {0,1},{2,3},{4,5},{6}
    const int cnt   = (pq < 3) ? 2 : 1;
    const int jrow  = lane & 31;
    const int g     = lane >> 5;

    const int arow0 = 64 * mg + jrow;          // m-tile 0 of this m-group
    const int arow1 = 64 * mg + 32 + jrow;     // m-tile 1
    const int te0   = (arow0 <= 100) ? arow0 : 50;
    const int te1   = (arow1 <= 100) ? arow1 : 50;
    const int ab0   = 160 * te0 - 200 + g * 8;
    const int ab1   = 160 * te1 - 200 + g * 8;

    const uint4* __restrict__ btg = (const uint4*)Bt;   // 3584 uint4 per kc

    // ---- prologue: A(0) into ac regs; stage B(0) into buffer 0
    f32x8 ac00 = loadA8(x, ab0);
    f32x8 ac01 = loadA8(x, ab0 + 16);
    f32x8 ac10 = loadA8(x, ab1);
    f32x8 ac11 = loadA8(x, ab1 + 16);
    {
        uint4 r0 = btg[0 * 512 + tid], r1 = btg[1 * 512 + tid];
        uint4 r2 = btg[2 * 512 + tid], r3 = btg[3 * 512 + tid];
        uint4 r4 = btg[4 * 512 + tid], r5 = btg[5 * 512 + tid];
        uint4 r6 = btg[6 * 512 + tid];
        uint4* dst = (uint4*)smem;
        dst[0 * 512 + tid] = r0; dst[1 * 512 + tid] = r1;
        dst[2 * 512 + tid] = r2; dst[3 * 512 + tid] = r3;
        dst[4 * 512 + tid] = r4; dst[5 * 512 + tid] = r5;
        dst[6 * 512 + tid] = r6;
    }
    __syncthreads();

    f32x16 accR[2][2], accI[2][2];     // [mt][i] re / im accumulators
    #pragma unroll
    for (int mt = 0; mt < 2; ++mt)
        #pragma unroll
        for (int i = 0; i < 2; ++i)
            #pragma unroll
            for (int e = 0; e < 16; ++e) { accR[mt][i][e] = 0.0f; accI[mt][i][e] = 0.0f; }

    int curoff = 0;
    for (int kc = 0; kc < 13; ++kc) {
        const bool pre = (kc < 12);

        // split current A first (frees ac registers for the next-kc loads)
        ASplit S00 = splitA(ac00);   // mt0 s0
        ASplit S01 = splitA(ac01);   // mt0 s1
        ASplit S10 = splitA(ac10);   // mt1 s0
        ASplit S11 = splitA(ac11);   // mt1 s1

        uint4 r0, r1, r2, r3, r4, r5, r6;
        if (pre) {
            // rr issued FIRST: the ds_write below waits vmcnt(4), leaving
            // the 4 A loads in flight; A is consumed only after the barrier.
            const uint4* src = btg + (kc + 1) * 3584;
            r0 = src[0 * 512 + tid]; r1 = src[1 * 512 + tid];
            r2 = src[2 * 512 + tid]; r3 = src[3 * 512 + tid];
            r4 = src[4 * 512 + tid]; r5 = src[5 * 512 + tid];
            r6 = src[6 * 512 + tid];
            ac00 = loadA8(x, ab0 + (kc + 1) * 32);
            ac01 = loadA8(x, ab0 + (kc + 1) * 32 + 16);
            ac10 = loadA8(x, ab1 + (kc + 1) * 32);
            ac11 = loadA8(x, ab1 + (kc + 1) * 32 + 16);
        }

        const unsigned short* bs = (const unsigned short*)(smem + curoff);
        #pragma unroll
        for (int s = 0; s < 2; ++s) {
            const short8 Ah0 = s ? S01.h : S00.h;
            const short8 Al0 = s ? S01.l : S00.l;
            const short8 Ah1 = s ? S11.h : S10.h;
            const short8 Al1 = s ? S11.l : S10.l;
            const int part = s * 2 + g;
            const int bhof = part * 3584;          // [pl=0][part] base (shorts)
            const int blof = (4 + part) * 3584;    // [pl=1][part]
            #pragma unroll
            for (int i = 0; i < 2; ++i) {
                if (i < cnt) {
                    const int p = pbase + i;
                    const int roR = p * 32 + jrow;          // re tile p
                    const int roI = (p + 7) * 32 + jrow;    // im tile p+7
                    short8 BhR = *(const short8*)(bs + bhof + roR * 8);
                    short8 BlR = *(const short8*)(bs + blof + roR * 8);
                    short8 BhI = *(const short8*)(bs + bhof + roI * 8);
                    short8 BlI = *(const short8*)(bs + blof + roI * 8);
                    accR[0][i] = __builtin_amdgcn_mfma_f32_32x32x16_bf16(Ah0, BhR, accR[0][i], 0, 0, 0);
                    accR[0][i] = __builtin_amdgcn_mfma_f32_32x32x16_bf16(Ah0, BlR, accR[0][i], 0, 0, 0);
                    accR[0][i] = __builtin_amdgcn_mfma_f32_32x32x16_bf16(Al0, BhR, accR[0][i], 0, 0, 0);
                    accR[1][i] = __builtin_amdgcn_mfma_f32_32x32x16_bf16(Ah1, BhR, accR[1][i], 0, 0, 0);
                    accR[1][i] = __builtin_amdgcn_mfma_f32_32x32x16_bf16(Ah1, BlR, accR[1][i], 0, 0, 0);
                    accR[1][i] = __builtin_amdgcn_mfma_f32_32x32x16_bf16(Al1, BhR, accR[1][i], 0, 0, 0);
                    accI[0][i] = __builtin_amdgcn_mfma_f32_32x32x16_bf16(Ah0, BhI, accI[0][i], 0, 0, 0);
                    accI[0][i] = __builtin_amdgcn_mfma_f32_32x32x16_bf16(Ah0, BlI, accI[0][i], 0, 0, 0);
                    accI[0][i] = __builtin_amdgcn_mfma_f32_32x32x16_bf16(Al0, BhI, accI[0][i], 0, 0, 0);
                    accI[1][i] = __builtin_amdgcn_mfma_f32_32x32x16_bf16(Ah1, BhI, accI[1][i], 0, 0, 0);
                    accI[1][i] = __builtin_amdgcn_mfma_f32_32x32x16_bf16(Ah1, BlI, accI[1][i], 0, 0, 0);
                    accI[1][i] = __builtin_amdgcn_mfma_f32_32x32x16_bf16(Al1, BhI, accI[1][i], 0, 0, 0);
                }
            }
        }

        if (pre) {
            uint4* dst = (uint4*)(smem + (curoff ^ 57344));
            dst[0 * 512 + tid] = r0; dst[1 * 512 + tid] = r1;
            dst[2 * 512 + tid] = r2; dst[3 * 512 + tid] = r3;
            dst[4 * 512 + tid] = r4; dst[5 * 512 + tid] = r5;
            dst[6 * 512 + tid] = r6;
        }
        __syncthreads();
        curoff ^= 57344;
    }

    // ---- epilogue: magnitude fully in-register, single write pass
    #pragma unroll
    for (int mt = 0; mt < 2; ++mt) {
        #pragma unroll
        for (int i = 0; i < 2; ++i) {
            if (i < cnt) {
                const int p = pbase + i;
                const int k = p * 32 + jrow;
                if (k <= 200) {
                    #pragma unroll
                    for (int r = 0; r < 16; ++r) {
                        int t = 64 * mg + 32 * mt + (r & 3) + 8 * (r >> 2) + 4 * g;
                        if (t <= 100) {
                            float re = accR[mt][i][r];
                            float im = accI[mt][i][r];
                            mags[t * MSTR + k] = sqrtf(re * re + im * im);
                        }
                    }
                }
            }
        }
    }
    __syncthreads();

    // ---- filterbank: lane = t (wave-uniform k-loop, conflict-free reads)
    {
        const int t0 = lane;
        const int t1v = 64 + lane;
        const int t1 = (t1v <= 100) ? t1v : 100;   // clamped read, guarded store
        #pragma unroll
        for (int i = 0; i < 8; ++i) {
            const int c = w * 8 + i;
            const float ctr = fctr[c];
            const float inv = finv[c];
            const int ks = fks[c], ke = fke[c];
            float a0 = 0.0f, a1 = 0.0f;
            for (int k = ks; k <= ke; ++k) {
                float resp = 1.0f - fabsf(40.0f * (float)k - ctr) * inv;
                a0 = fmaf(resp, mags[t0 * MSTR + k], a0);
                a1 = fmaf(resp, mags[t1 * MSTR + k], a1);
            }
            fbuf[c * 101 + t0] = a0;
            if (t1v <= 100) fbuf[c * 101 + t1v] = a1;
        }
    }
    __syncthreads();

    // ---- global LayerNorm (one-pass: sum + sumsq)
    float s = 0.0f, ss = 0.0f;
    for (int i = tid; i < 6464; i += BLOCK) {
        float vv = fbuf[i];
        s += vv;
        ss = fmaf(vv, vv, ss);
    }
    #pragma unroll
    for (int off = 32; off > 0; off >>= 1) {
        s  += __shfl_down(s,  off, 64);
        ss += __shfl_down(ss, off, 64);
    }
    if (lane == 0) { red[w] = s; red[8 + w] = ss; }
    __syncthreads();
    if (tid == 0) {
        float ts = 0.0f, tss = 0.0f;
        for (int i = 0; i < 8; ++i) { ts += red[i]; tss += red[8 + i]; }
        float mu = ts * (1.0f / 6464.0f);
        stats[0] = mu;
        stats[1] = tss * (1.0f / 6464.0f) - mu * mu;
    }
    __syncthreads();
    const float mu   = stats[0];
    const float isig = 1.0f / sqrtf(stats[1] + 1e-5f);

    // ---- log-energy + interp 101->64 + transposed store
    for (int idx = tid; idx < 4096; idx += BLOCK) {
        const int to = idx >> 6;
        const int c  = idx & 63;
        float pos = ((float)to + 0.5f) * 1.578125f - 0.5f;
        pos = fminf(fmaxf(pos, 0.0f), 100.0f);
        int i0 = (int)floorf(pos);
        int i1 = i0 + 1; if (i1 > 100) i1 = 100;
        float fr = pos - (float)i0;
        float wc = ln_w[c], bc = ln_b[c];
        float x0 = fbuf[c * 101 + i0];
        float x1 = fbuf[c * 101 + i1];
        float y0 = fmaf(wc, (x0 - mu) * isig, bc);
        float y1 = fmaf(wc, (x1 - mu) * isig, bc);
        float l0 = log10f(fmaf(y0, y0, 1e-6f));
        float l1 = log10f(fmaf(y1, y1, 1e-6f));
        out[b * 4096 + idx] = l0 * (1.0f - fr) + l1 * fr;
    }
}

// ---------------------------------------------------------------------------
// Fallback (R2 VALU path) if ws_size is too small for the B table.
// ---------------------------------------------------------------------------
__global__ __launch_bounds__(512, 2)
void fse_main_valu(const float* __restrict__ wav,
                   const float* __restrict__ low_hz_,
                   const float* __restrict__ band_hz_,
                   const float* __restrict__ ln_w,
                   const float* __restrict__ ln_b,
                   float* __restrict__ out)
{
    __shared__ float  xp[16400];
    __shared__ float2 Xs[8][204];
    __shared__ float  mags[8][204];
    __shared__ float  fbuf[64 * 101];
    __shared__ float  fctr[64], finv[64];
    __shared__ int    fks[64], fke[64];
    __shared__ float  red[8];
    __shared__ float  stats[2];

    const int b    = blockIdx.x;
    const int tid  = threadIdx.x;
    const int w    = tid >> 6;
    const int lane = tid & 63;
    const float* __restrict__ x = wav + b * 16000;

    for (int i = tid; i < 16400; i += BLOCK) {
        int p = i - 200;
        p = (p < 0) ? -p : p;
        p = (p > 15999) ? (31998 - p) : p;
        xp[i] = x[p];
    }
    if (tid < 64) {
        float lo = 50.0f + fabsf(low_hz_[tid]);
        float hi = lo + 50.0f + fabsf(band_hz_[tid]);
        hi = fminf(fmaxf(hi, 50.0f), 8000.0f);
        float ctr = 0.5f * (lo + hi);
        float hbw = 0.5f * (hi - lo);
        int ks = (int)ceilf(lo * 0.025f);
        if (ks < 0) ks = 0;
        while (40.0f * (float)ks < lo) ++ks;
        while (ks > 0 && 40.0f * (float)(ks - 1) >= lo) --ks;
        int ke = (int)floorf(hi * 0.025f);
        if (ke > 200) ke = 200;
        while (40.0f * (float)ke > hi) --ke;
        while (ke < 200 && 40.0f * (float)(ke + 1) <= hi) ++ke;
        fctr[tid] = ctr;
        finv[tid] = (hbw > 0.0f) ? (1.0f / hbw) : 0.0f;
        fks[tid]  = ks;
        fke[tid]  = ke;
    }
    __syncthreads();

    const float cctr = fctr[lane];
    const float cinv = finv[lane];
    const int   cks  = fks[lane];
    const int   cke  = fke[lane];

    float reX[4][13], imX[4][13];
    const float2* __restrict__ xp2 = (const float2*)xp;
    float c0[4], s0[4], c1[4], s1[4], cd[4], sd[4];
    #pragma unroll
    for (int m = 0; m < 4; ++m) {
        const int k = m * 64 + lane;
        const float th = -0.015707963267948966f * (float)k;
        sincosf(th, &s1[m], &c1[m]);
        sincosf(th + th, &sd[m], &cd[m]);
        c0[m] = 1.0f; s0[m] = 0.0f;
        #pragma unroll
        for (int j = 0; j < 13; ++j) { reX[m][j] = 0.0f; imX[m][j] = 0.0f; }
    }
    const int o12 = (w < 5) ? 640 * 12 : 0;
    int ib = 80 * w;
    #pragma unroll 2
    for (int h = 0; h < 200; ++h) {
        #pragma unroll
        for (int j = 0; j < 13; ++j) {
            const int off = (j == 12) ? o12 : 640 * j;
            float2 f = xp2[ib + off];
            #pragma unroll
            for (int m = 0; m < 4; ++m) {
                reX[m][j] = fmaf(f.x, c0[m], reX[m][j]);
                imX[m][j] = fmaf(f.x, s0[m], imX[m][j]);
                reX[m][j] = fmaf(f.y, c1[m], reX[m][j]);
                imX[m][j] = fmaf(f.y, s1[m], imX[m][j]);
            }
        }
        #pragma unroll
        for (int m = 0; m < 4; ++m) {
            float nc0 = fmaf(c0[m], cd[m], -(s0[m] * sd[m]));
            float ns0 = fmaf(s0[m], cd[m],  (c0[m] * sd[m]));
            float nc1 = fmaf(c1[m], cd[m], -(s1[m] * sd[m]));
            float ns1 = fmaf(s1[m], cd[m],  (c1[m] * sd[m]));
            c0[m] = nc0; s0[m] = ns0; c1[m] = nc1; s1[m] = ns1;
        }
        ++ib;
    }

    float2* __restrict__ myX   = &Xs[w][0];
    float*  __restrict__ mymag = &mags[w][0];
    for (int j = 0; j < 13; ++j) {
        const int t = w + 8 * j;
        if (t > 100) break;
        #pragma unroll
        for (int m = 0; m < 4; ++m) {
            const int k = m * 64 + lane;
            if (k < 202) myX[k] = make_float2(reX[m][j], imX[m][j]);
        }
        asm volatile("s_waitcnt lgkmcnt(0)" ::: "memory");
        #pragma unroll
        for (int m = 0; m < 4; ++m) {
            const int k = m * 64 + lane;
            if (k <= 200) {
                float2 xm = (k == 0) ? myX[1] : myX[k - 1];
                float imm = (k == 0) ? -xm.y : xm.y;
                float2 xq = myX[k + 1];
                float rw = 0.5f * reX[m][j] - 0.25f * (xm.x + xq.x);
                float iw = 0.5f * imX[m][j] - 0.25f * (imm  + xq.y);
                mymag[k] = sqrtf(rw * rw + iw * iw);
            }
        }
        asm volatile("s_waitcnt lgkmcnt(0)" ::: "memory");
        float acc = 0.0f;
        for (int k = cks; k <= cke; ++k) {
            float resp = 1.0f - fabsf(40.0f * (float)k - cctr) * cinv;
            acc = fmaf(resp, mymag[k], acc);
        }
        fbuf[lane * 101 + t] = acc;
    }
    __syncthreads();

    float s = 0.0f;
    for (int i = tid; i < 6464; i += BLOCK) s += fbuf[i];
    #pragma unroll
    for (int off = 32; off > 0; off >>= 1) s += __shfl_down(s, off, 64);
    if (lane == 0) red[w] = s;
    __syncthreads();
    if (tid == 0) {
        float tsum = 0.0f;
        for (int i = 0; i < 8; ++i) tsum += red[i];
        stats[0] = tsum * (1.0f / 6464.0f);
    }
    __syncthreads();
    const float mu = stats[0];
    float v = 0.0f;
    for (int i = tid; i < 6464; i += BLOCK) { float d = fbuf[i] - mu; v = fmaf(d, d, v); }
    #pragma unroll
    for (int off = 32; off > 0; off >>= 1) v += __shfl_down(v, off, 64);
    if (lane == 0) red[w] = v;
    __syncthreads();
    if (tid == 0) {
        float tsum = 0.0f;
        for (int i = 0; i < 8; ++i) tsum += red[i];
        stats[1] = tsum * (1.0f / 6464.0f);
    }
    __syncthreads();
    const float var  = stats[1];
    const float isig = 1.0f / sqrtf(var + 1e-5f);

    for (int idx = tid; idx < 4096; idx += BLOCK) {
        const int to = idx >> 6;
        const int c  = idx & 63;
        float pos = ((float)to + 0.5f) * 1.578125f - 0.5f;
        pos = fminf(fmaxf(pos, 0.0f), 100.0f);
        int i0 = (int)floorf(pos);
        int i1 = i0 + 1; if (i1 > 100) i1 = 100;
        float fr = pos - (float)i0;
        float wc = ln_w[c], bc = ln_b[c];
        float x0 = fbuf[c * 101 + i0];
        float x1 = fbuf[c * 101 + i1];
        float y0 = fmaf(wc, (x0 - mu) * isig, bc);
        float y1 = fmaf(wc, (x1 - mu) * isig, bc);
        float l0 = log10f(fmaf(y0, y0, 1e-6f));
        float l1 = log10f(fmaf(y1, y1, 1e-6f));
        out[b * 4096 + idx] = l0 * (1.0f - fr) + l1 * fr;
    }
}

extern "C" void kernel_launch(void* const* d_in, const int* in_sizes, int n_in,
                              void* d_out, int out_size, void* d_ws, size_t ws_size,
                              hipStream_t stream)
{
    const float* wav = (const float*)d_in[0];
    const float* lo  = (const float*)d_in[1];
    const float* bd  = (const float*)d_in[2];
    const float* lw  = (const float*)d_in[3];
    const float* lb  = (const float*)d_in[4];
    float* out = (float*)d_out;

    fse_filters<<<(64 * 201 + 255) / 256, 256, 0, stream>>>(lo, bd, out + 1024 * 4096);

    const size_t BNEED = (size_t)372736 * sizeof(unsigned short); // 745472 B
    if (ws_size >= BNEED) {
        unsigned short* Bts = (unsigned short*)d_ws;
        fse_setup_B<<<(372736 + 255) / 256, 256, 0, stream>>>(Bts);
        fse_main_mfma<<<1024, BLOCK, 0, stream>>>(wav, lo, bd, lw, lb, Bts, out);
    } else {
        fse_main_valu<<<1024, BLOCK, 0, stream>>>(wav, lo, bd, lw, lb, out);
    }
}

// Round 10
// 249.695 us; speedup vs baseline: 1.2058x; 1.0428x over previous
//
#include <hip/hip_runtime.h>
#include <math.h>

typedef __attribute__((ext_vector_type(8))) short short8;
typedef __attribute__((ext_vector_type(16))) float f32x16;
typedef __attribute__((ext_vector_type(8))) float f32x8;

__device__ inline unsigned short f2bf(float x) {
    unsigned u = __float_as_uint(x);
    unsigned r = u + 0x7fffu + ((u >> 16) & 1u);
    return (unsigned short)(r >> 16);
}

struct ASplit { short8 h, l; };

__device__ inline ASplit splitA(f32x8 v) {
    unsigned ah[4], al[4];
    #pragma unroll
    for (int q = 0; q < 4; ++q) {
        unsigned short h0 = f2bf(v[2*q]),   h1 = f2bf(v[2*q+1]);
        float hf0 = __uint_as_float((unsigned)h0 << 16);
        float hf1 = __uint_as_float((unsigned)h1 << 16);
        unsigned short l0 = f2bf(v[2*q] - hf0), l1 = f2bf(v[2*q+1] - hf1);
        ah[q] = (unsigned)h0 | ((unsigned)h1 << 16);
        al[q] = (unsigned)l0 | ((unsigned)l1 << 16);
    }
    ASplit r;
    r.h = __builtin_bit_cast(short8, *(uint4*)ah);
    r.l = __builtin_bit_cast(short8, *(uint4*)al);
    return r;
}

__device__ inline f32x8 loadA8(const float* __restrict__ x, int i0) {
    f32x8 r;
    if (i0 >= 0 && i0 <= 15992) {
        float4 a0 = *(const float4*)(x + i0);
        float4 a1 = *(const float4*)(x + i0 + 4);
        r[0] = a0.x; r[1] = a0.y; r[2] = a0.z; r[3] = a0.w;
        r[4] = a1.x; r[5] = a1.y; r[6] = a1.z; r[7] = a1.w;
    } else {
        #pragma unroll
        for (int e = 0; e < 8; ++e) {
            int p = i0 + e;
            p = (p < 0) ? -p : p;
            p = (p > 15999) ? (31998 - p) : p;
            r[e] = x[p];
        }
    }
    return r;
}

__device__ inline void filter_params(int c, const float* low_hz_, const float* band_hz_,
                                     float* fctr, float* finv, int* fks, int* fke) {
    float lo = 50.0f + fabsf(low_hz_[c]);
    float hi = lo + 50.0f + fabsf(band_hz_[c]);
    hi = fminf(fmaxf(hi, 50.0f), 8000.0f);
    float ctr = 0.5f * (lo + hi);
    float hbw = 0.5f * (hi - lo);
    int ks = (int)ceilf(lo * 0.025f);
    if (ks < 0) ks = 0;
    while (40.0f * (float)ks < lo) ++ks;
    while (ks > 0 && 40.0f * (float)(ks - 1) >= lo) --ks;
    int ke = (int)floorf(hi * 0.025f);
    if (ke > 200) ke = 200;
    while (40.0f * (float)ke > hi) --ke;
    while (ke < 200 && 40.0f * (float)(ke + 1) <= hi) ++ke;
    fctr[c] = ctr;
    finv[c] = (hbw > 0.0f) ? (1.0f / hbw) : 0.0f;
    fks[c]  = ks;
    fke[c]  = ke;
}

// ---------------------------------------------------------------------------
// Kernel 1: filters output (64 x 201) -> tail of d_out.
// ---------------------------------------------------------------------------
__global__ void fse_filters(const float* __restrict__ low_hz_,
                            const float* __restrict__ band_hz_,
                            float* __restrict__ out)
{
    int idx = blockIdx.x * 256 + threadIdx.x;
    if (idx >= 64 * 201) return;
    int c = idx / 201;
    int k = idx - c * 201;
    float lo = 50.0f + fabsf(low_hz_[c]);
    float hi = lo + 50.0f + fabsf(band_hz_[c]);
    hi = fminf(fmaxf(hi, 50.0f), 8000.0f);
    float ctr = 0.5f * (lo + hi);
    float hbw = 0.5f * (hi - lo);
    float fq = 40.0f * (float)k;
    float resp = 1.0f - fabsf(fq - ctr) / hbw;
    out[idx] = (fq >= lo && fq <= hi) ? resp : 0.0f;
}

// ---------------------------------------------------------------------------
// Kernel 1b: B in chunk-linear layout: Bt[kc][pl][part][row][8] bf16 (hi/lo).
// ---------------------------------------------------------------------------
__global__ void fse_setup_B(unsigned short* __restrict__ bt)
{
    int idx = blockIdx.x * 256 + threadIdx.x;   // 13*2*4*448*8 = 372736
    if (idx >= 372736) return;
    int e   = idx & 7;
    int t   = idx >> 3;
    int row = t % 448;
    int q   = t / 448;
    int p   = q & 3;
    int pl  = (q >> 2) & 1;
    int kc  = q >> 3;
    int n   = kc * 32 + p * 8 + e;
    float v = 0.0f;
    if (n < 400) {
        int bin = -1, isim = 0;
        if (row <= 200) bin = row;
        else if (row >= 224 && row <= 424) { bin = row - 224; isim = 1; }
        if (bin >= 0) {
            int a = (bin * n) % 400;
            float th = 6.283185307179586f * ((float)a / 400.0f);
            float sn, cs;
            sincosf(th, &sn, &cs);
            float wn = 0.5f - 0.5f * cosf(6.283185307179586f * ((float)n / 400.0f));
            v = isim ? (-wn * sn) : (wn * cs);
        }
    }
    unsigned short h = f2bf(v);
    float hf = __uint_as_float((unsigned)h << 16);
    unsigned short l = f2bf(v - hf);
    bt[idx] = pl ? l : h;
}

// ---------------------------------------------------------------------------
// Kernel A (split path): 2 blocks per batch item (64 output rows each).
//  Per-wave acc <= 64 regs; __launch_bounds__(512,4) -> <=128 VGPR -> 4
//  waves/SIMD; LDS 56KB B-chunk (single-buffered DMA, overlaid by mags in
//  epilogue) -> 2 blocks/CU. Cross-block overlap covers DMA/barrier stalls.
//  Wave = (mt = w>>2, pq = w&3): mt is the 32-row tile within the 64-row
//  half; pq owns (re,im) bin-tile pairs {0,1},{2,3},{4,5},{6}.
//  Writes filtered[b][c][t] fp32 to d_ws.
// ---------------------------------------------------------------------------
__global__ __launch_bounds__(512, 4)
void fse_gemm(const float* __restrict__ wav,
              const float* __restrict__ low_hz_,
              const float* __restrict__ band_hz_,
              const unsigned short* __restrict__ Bt,
              float* __restrict__ filt)
{
    __shared__ __align__(16) char smem[57344];   // B chunk | mags[64][201] overlay
    __shared__ float fctr[64], finv[64];
    __shared__ int   fks[64], fke[64];
    float* mags = (float*)smem;

    const int bid  = blockIdx.x;
    const int b    = bid >> 1;
    const int half = bid & 1;
    const int tid  = threadIdx.x;
    const int w    = tid >> 6;
    const int lane = tid & 63;
    const float* __restrict__ x = wav + b * 16000;

    if (tid < 64) filter_params(tid, low_hz_, band_hz_, fctr, finv, fks, fke);

    const int mt    = w >> 2;          // 0,1: 32-row tile within this half
    const int pq    = w & 3;
    const int pbase = pq * 2;
    const int cnt   = (pq < 3) ? 2 : 1;
    const int jrow  = lane & 31;
    const int g     = lane >> 5;

    const int arow = 64 * half + 32 * mt + jrow;
    const int te   = (arow <= 100) ? arow : 50;
    const int ab   = 160 * te - 200 + g * 8;

    f32x16 accR[2], accI[2];
    #pragma unroll
    for (int i = 0; i < 2; ++i)
        #pragma unroll
        for (int e = 0; e < 16; ++e) { accR[i][e] = 0.0f; accI[i][e] = 0.0f; }

    for (int kc = 0; kc < 13; ++kc) {
        __syncthreads();   // previous chunk's reads complete
        {   // DMA chunk kc: wave-uniform LDS base + lane*16, linear layout
            const uint4* src = (const uint4*)Bt + kc * 3584 + (w << 6) + lane;
            char* dstb = smem + (w << 6) * 16;
            #pragma unroll
            for (int i = 0; i < 7; ++i) {
                __builtin_amdgcn_global_load_lds(
                    (const __attribute__((address_space(1))) unsigned*)(src + i * 512),
                    (__attribute__((address_space(3))) unsigned*)(dstb + i * 8192),
                    16, 0, 0);
            }
        }
        __syncthreads();   // vmcnt drained -> chunk visible

        f32x8 a0 = loadA8(x, ab + kc * 32);
        f32x8 a1 = loadA8(x, ab + kc * 32 + 16);

        const unsigned short* bs = (const unsigned short*)smem;
        #pragma unroll
        for (int s = 0; s < 2; ++s) {
            ASplit S = splitA(s ? a1 : a0);
            const int part = s * 2 + g;
            const int bhof = part * 3584;
            const int blof = (4 + part) * 3584;
            #pragma unroll
            for (int i = 0; i < 2; ++i) {
                if (i < cnt) {
                    const int p = pbase + i;
                    const int roR = p * 32 + jrow;
                    const int roI = (p + 7) * 32 + jrow;
                    short8 BhR = *(const short8*)(bs + bhof + roR * 8);
                    short8 BlR = *(const short8*)(bs + blof + roR * 8);
                    short8 BhI = *(const short8*)(bs + bhof + roI * 8);
                    short8 BlI = *(const short8*)(bs + blof + roI * 8);
                    accR[i] = __builtin_amdgcn_mfma_f32_32x32x16_bf16(S.h, BhR, accR[i], 0, 0, 0);
                    accR[i] = __builtin_amdgcn_mfma_f32_32x32x16_bf16(S.h, BlR, accR[i], 0, 0, 0);
                    accR[i] = __builtin_amdgcn_mfma_f32_32x32x16_bf16(S.l, BhR, accR[i], 0, 0, 0);
                    accI[i] = __builtin_amdgcn_mfma_f32_32x32x16_bf16(S.h, BhI, accI[i], 0, 0, 0);
                    accI[i] = __builtin_amdgcn_mfma_f32_32x32x16_bf16(S.h, BlI, accI[i], 0, 0, 0);
                    accI[i] = __builtin_amdgcn_mfma_f32_32x32x16_bf16(S.l, BhI, accI[i], 0, 0, 0);
                }
            }
        }
    }

    __syncthreads();   // B reads done; smem reusable as mags[64][201]

    // magnitude in-register, single LDS write pass (t local to this half)
    #pragma unroll
    for (int i = 0; i < 2; ++i) {
        if (i < cnt) {
            const int k = (pbase + i) * 32 + jrow;
            if (k <= 200) {
                #pragma unroll
                for (int r = 0; r < 16; ++r) {
                    int tl = 32 * mt + (r & 3) + 8 * (r >> 2) + 4 * g;
                    float re = accR[i][r];
                    float im = accI[i][r];
                    mags[tl * 201 + k] = sqrtf(re * re + im * im);
                }
            }
        }
    }
    __syncthreads();

    // filterbank: lane = t_local (64 lanes = 64 rows), wave-uniform k-loop
    const int tg = 64 * half + lane;
    #pragma unroll
    for (int i = 0; i < 8; ++i) {
        const int c = w * 8 + i;
        const float ctr = fctr[c];
        const float inv = finv[c];
        const int ks = fks[c], ke = fke[c];
        float a = 0.0f;
        for (int k = ks; k <= ke; ++k) {
            float resp = 1.0f - fabsf(40.0f * (float)k - ctr) * inv;
            a = fmaf(resp, mags[lane * 201 + k], a);
        }
        if (tg <= 100) filt[b * 6464 + c * 101 + tg] = a;
    }
}

// ---------------------------------------------------------------------------
// Kernel B (split path): per batch item, LN + log10 + interp + store.
// Memory-bound: reads 26.5 MB filtered, writes 16.7 MB out.
// ---------------------------------------------------------------------------
__global__ __launch_bounds__(256)
void fse_post(const float* __restrict__ filt,
              const float* __restrict__ ln_w,
              const float* __restrict__ ln_b,
              float* __restrict__ out)
{
    __shared__ float fbuf[6464];
    __shared__ float red[8];
    __shared__ float stats[2];
    const int b    = blockIdx.x;
    const int tid  = threadIdx.x;
    const int w    = tid >> 6;
    const int lane = tid & 63;
    const float* __restrict__ src = filt + b * 6464;

    float s = 0.0f, ss = 0.0f;
    for (int i = tid; i < 6464; i += 256) {
        float v = src[i];
        fbuf[i] = v;
        s += v;
        ss = fmaf(v, v, ss);
    }
    #pragma unroll
    for (int off = 32; off > 0; off >>= 1) {
        s  += __shfl_down(s,  off, 64);
        ss += __shfl_down(ss, off, 64);
    }
    if (lane == 0) { red[w] = s; red[4 + w] = ss; }
    __syncthreads();
    if (tid == 0) {
        float ts = 0.0f, tss = 0.0f;
        for (int i = 0; i < 4; ++i) { ts += red[i]; tss += red[4 + i]; }
        float mu = ts * (1.0f / 6464.0f);
        stats[0] = mu;
        stats[1] = tss * (1.0f / 6464.0f) - mu * mu;
    }
    __syncthreads();
    const float mu   = stats[0];
    const float isig = 1.0f / sqrtf(stats[1] + 1e-5f);

    for (int idx = tid; idx < 4096; idx += 256) {
        const int to = idx >> 6;
        const int c  = idx & 63;
        float pos = ((float)to + 0.5f) * 1.578125f - 0.5f;
        pos = fminf(fmaxf(pos, 0.0f), 100.0f);
        int i0 = (int)floorf(pos);
        int i1 = i0 + 1; if (i1 > 100) i1 = 100;
        float fr = pos - (float)i0;
        float wc = ln_w[c], bc = ln_b[c];
        float x0 = fbuf[c * 101 + i0];
        float x1 = fbuf[c * 101 + i1];
        float y0 = fmaf(wc, (x0 - mu) * isig, bc);
        float y1 = fmaf(wc, (x1 - mu) * isig, bc);
        float l0 = log10f(fmaf(y0, y0, 1e-6f));
        float l1 = log10f(fmaf(y1, y1, 1e-6f));
        out[b * 4096 + idx] = l0 * (1.0f - fr) + l1 * fr;
    }
}

// ---------------------------------------------------------------------------
// Fallback: R6 fused kernel (best known single-kernel path), used when
// ws_size < 27.2 MB. Verbatim from round 6 (232 us).
// ---------------------------------------------------------------------------
#define MSTR 209
__global__ __launch_bounds__(512, 2)
void fse_main_fused(const float* __restrict__ wav,
                    const float* __restrict__ low_hz_,
                    const float* __restrict__ band_hz_,
                    const float* __restrict__ ln_w,
                    const float* __restrict__ ln_b,
                    const unsigned short* __restrict__ Bt,
                    float* __restrict__ out)
{
    __shared__ __align__(16) char smem[114688];
    float* mags = (float*)smem;
    float* fbuf = (float*)(smem + 84544);
    __shared__ float fctr[64], finv[64];
    __shared__ int   fks[64], fke[64];
    __shared__ float red[16];
    __shared__ float stats[2];

    const int b    = blockIdx.x;
    const int tid  = threadIdx.x;
    const int w    = tid >> 6;
    const int lane = tid & 63;
    const float* __restrict__ x = wav + b * 16000;

    if (tid < 64) filter_params(tid, low_hz_, band_hz_, fctr, finv, fks, fke);

    const int mt   = w >> 1;
    const int half = w & 1;
    const int jrow = lane & 31;
    const int g    = lane >> 5;
    const int arow = mt * 32 + jrow;
    const int te   = (arow <= 100) ? arow : 50;
    const int abase = 160 * te - 200 + g * 8;

    const uint4* __restrict__ btg = (const uint4*)Bt;

    f32x8 ac0 = loadA8(x, abase);
    f32x8 ac1 = loadA8(x, abase + 16);
    {
        uint4 rr0 = btg[0 * 512 + tid], rr1 = btg[1 * 512 + tid];
        uint4 rr2 = btg[2 * 512 + tid], rr3 = btg[3 * 512 + tid];
        uint4 rr4 = btg[4 * 512 + tid], rr5 = btg[5 * 512 + tid];
        uint4 rr6 = btg[6 * 512 + tid];
        uint4* dst = (uint4*)smem;
        dst[0 * 512 + tid] = rr0; dst[1 * 512 + tid] = rr1;
        dst[2 * 512 + tid] = rr2; dst[3 * 512 + tid] = rr3;
        dst[4 * 512 + tid] = rr4; dst[5 * 512 + tid] = rr5;
        dst[6 * 512 + tid] = rr6;
    }
    __syncthreads();

    f32x16 acc[7];
    #pragma unroll
    for (int n = 0; n < 7; ++n)
        #pragma unroll
        for (int e = 0; e < 16; ++e) acc[n][e] = 0.0f;

    int curoff = 0;
    for (int kc = 0; kc < 13; ++kc) {
        const bool pre = (kc < 12);
        uint4 rr0, rr1, rr2, rr3, rr4, rr5, rr6;
        f32x8 an0, an1;
        if (pre) {
            const uint4* src = btg + (kc + 1) * 3584;
            rr0 = src[0 * 512 + tid]; rr1 = src[1 * 512 + tid];
            rr2 = src[2 * 512 + tid]; rr3 = src[3 * 512 + tid];
            rr4 = src[4 * 512 + tid]; rr5 = src[5 * 512 + tid];
            rr6 = src[6 * 512 + tid];
            an0 = loadA8(x, abase + (kc + 1) * 32);
            an1 = loadA8(x, abase + (kc + 1) * 32 + 16);
        }
        ASplit A0 = splitA(ac0);
        ASplit A1 = splitA(ac1);

        const unsigned short* bs = (const unsigned short*)(smem + curoff);
        #pragma unroll
        for (int s = 0; s < 2; ++s) {
            const short8 Ah = s ? A1.h : A0.h;
            const short8 Al = s ? A1.l : A0.l;
            const int pb = (s * 2 + g) * 448;
            #pragma unroll
            for (int n = 0; n < 7; ++n) {
                const int ro = (half * 7 + n) * 32 + jrow;
                short8 Bh = *(const short8*)(bs + (pb + ro) * 8);
                short8 Bl = *(const short8*)(bs + 14336 + (pb + ro) * 8);
                acc[n] = __builtin_amdgcn_mfma_f32_32x32x16_bf16(Ah, Bh, acc[n], 0, 0, 0);
                acc[n] = __builtin_amdgcn_mfma_f32_32x32x16_bf16(Ah, Bl, acc[n], 0, 0, 0);
                acc[n] = __builtin_amdgcn_mfma_f32_32x32x16_bf16(Al, Bh, acc[n], 0, 0, 0);
            }
        }
        if (pre) {
            uint4* dst = (uint4*)(smem + (curoff ^ 57344));
            dst[0 * 512 + tid] = rr0; dst[1 * 512 + tid] = rr1;
            dst[2 * 512 + tid] = rr2; dst[3 * 512 + tid] = rr3;
            dst[4 * 512 + tid] = rr4; dst[5 * 512 + tid] = rr5;
            dst[6 * 512 + tid] = rr6;
        }
        __syncthreads();
        if (pre) { ac0 = an0; ac1 = an1; }
        curoff ^= 57344;
    }

    if (half == 0) {
        #pragma unroll
        for (int n = 0; n < 7; ++n) {
            int k = n * 32 + jrow;
            if (k <= 200) {
                #pragma unroll
                for (int r = 0; r < 16; ++r) {
                    int t = mt * 32 + (r & 3) + 8 * (r >> 2) + 4 * g;
                    if (t <= 100) mags[t * MSTR + k] = acc[n][r];
                }
            }
        }
    }
    __syncthreads();
    if (half == 1) {
        #pragma unroll
        for (int n = 0; n < 7; ++n) {
            int k = n * 32 + jrow;
            if (k <= 200) {
                #pragma unroll
                for (int r = 0; r < 16; ++r) {
                    int t = mt * 32 + (r & 3) + 8 * (r >> 2) + 4 * g;
                    if (t <= 100) {
                        float re = mags[t * MSTR + k];
                        float im = acc[n][r];
                        mags[t * MSTR + k] = sqrtf(re * re + im * im);
                    }
                }
            }
        }
    }
    __syncthreads();

    {
        const int t0 = lane;
        const int t1v = 64 + lane;
        const int t1 = (t1v <= 100) ? t1v : 100;
        #pragma unroll
        for (int i = 0; i < 8; ++i) {
            const int c = w * 8 + i;
            const float ctr = fctr[c];
            const float inv = finv[c];
            const int ks = fks[c], ke = fke[c];
            float a0 = 0.0f, a1 = 0.0f;
            for (int k = ks; k <= ke; ++k) {
                float resp = 1.0f - fabsf(40.0f * (float)k - ctr) * inv;
                a0 = fmaf(resp, mags[t0 * MSTR + k], a0);
                a1 = fmaf(resp, mags[t1 * MSTR + k], a1);
            }
            fbuf[c * 101 + t0] = a0;
            if (t1v <= 100) fbuf[c * 101 + t1v] = a1;
        }
    }
    __syncthreads();

    float s = 0.0f, ss = 0.0f;
    for (int i = tid; i < 6464; i += 512) {
        float vv = fbuf[i];
        s += vv;
        ss = fmaf(vv, vv, ss);
    }
    #pragma unroll
    for (int off = 32; off > 0; off >>= 1) {
        s  += __shfl_down(s,  off, 64);
        ss += __shfl_down(ss, off, 64);
    }
    if (lane == 0) { red[w] = s; red[8 + w] = ss; }
    __syncthreads();
    if (tid == 0) {
        float ts = 0.0f, tss = 0.0f;
        for (int i = 0; i < 8; ++i) { ts += red[i]; tss += red[8 + i]; }
        float mu = ts * (1.0f / 6464.0f);
        stats[0] = mu;
        stats[1] = tss * (1.0f / 6464.0f) - mu * mu;
    }
    __syncthreads();
    const float mu   = stats[0];
    const float isig = 1.0f / sqrtf(stats[1] + 1e-5f);

    for (int idx = tid; idx < 4096; idx += 512) {
        const int to = idx >> 6;
        const int c  = idx & 63;
        float pos = ((float)to + 0.5f) * 1.578125f - 0.5f;
        pos = fminf(fmaxf(pos, 0.0f), 100.0f);
        int i0 = (int)floorf(pos);
        int i1 = i0 + 1; if (i1 > 100) i1 = 100;
        float fr = pos - (float)i0;
        float wc = ln_w[c], bc = ln_b[c];
        float x0 = fbuf[c * 101 + i0];
        float x1 = fbuf[c * 101 + i1];
        float y0 = fmaf(wc, (x0 - mu) * isig, bc);
        float y1 = fmaf(wc, (x1 - mu) * isig, bc);
        float l0 = log10f(fmaf(y0, y0, 1e-6f));
        float l1 = log10f(fmaf(y1, y1, 1e-6f));
        out[b * 4096 + idx] = l0 * (1.0f - fr) + l1 * fr;
    }
}

extern "C" void kernel_launch(void* const* d_in, const int* in_sizes, int n_in,
                              void* d_out, int out_size, void* d_ws, size_t ws_size,
                              hipStream_t stream)
{
    const float* wav = (const float*)d_in[0];
    const float* lo  = (const float*)d_in[1];
    const float* bd  = (const float*)d_in[2];
    const float* lw  = (const float*)d_in[3];
    const float* lb  = (const float*)d_in[4];
    float* out = (float*)d_out;

    fse_filters<<<(64 * 201 + 255) / 256, 256, 0, stream>>>(lo, bd, out + 1024 * 4096);

    const size_t BN1 = 745472;                                  // B table
    const size_t BN2 = BN1 + (size_t)1024 * 6464 * 4;           // + filtered (27.2 MB)
    unsigned short* Bts = (unsigned short*)d_ws;
    fse_setup_B<<<(372736 + 255) / 256, 256, 0, stream>>>(Bts);

    if (ws_size >= BN2) {
        float* filt = (float*)((char*)d_ws + BN1);
        fse_gemm<<<2048, 512, 0, stream>>>(wav, lo, bd, Bts, filt);
        fse_post<<<1024, 256, 0, stream>>>(filt, lw, lb, out);
    } else {
        fse_main_fused<<<1024, 512, 0, stream>>>(wav, lo, bd, lw, lb, Bts, out);
    }
}

// Round 11
// 222.808 us; speedup vs baseline: 1.3513x; 1.1207x over previous
//
#include <hip/hip_runtime.h>
#include <math.h>

typedef __attribute__((ext_vector_type(8))) short short8;
typedef __attribute__((ext_vector_type(16))) float f32x16;
typedef __attribute__((ext_vector_type(8))) float f32x8;

__device__ inline unsigned short f2bf(float x) {
    unsigned u = __float_as_uint(x);
    unsigned r = u + 0x7fffu + ((u >> 16) & 1u);
    return (unsigned short)(r >> 16);
}

struct ASplit { short8 h, l; };

// rounded split (register code) — used by the fused fallback
__device__ inline ASplit splitA(f32x8 v) {
    unsigned ah[4], al[4];
    #pragma unroll
    for (int q = 0; q < 4; ++q) {
        unsigned short h0 = f2bf(v[2*q]),   h1 = f2bf(v[2*q+1]);
        float hf0 = __uint_as_float((unsigned)h0 << 16);
        float hf1 = __uint_as_float((unsigned)h1 << 16);
        unsigned short l0 = f2bf(v[2*q] - hf0), l1 = f2bf(v[2*q+1] - hf1);
        ah[q] = (unsigned)h0 | ((unsigned)h1 << 16);
        al[q] = (unsigned)l0 | ((unsigned)l1 << 16);
    }
    ASplit r;
    r.h = __builtin_bit_cast(short8, *(uint4*)ah);
    r.l = __builtin_bit_cast(short8, *(uint4*)al);
    return r;
}

// fast truncation split: 6 VALU per 2 values (perm-pack hi, sub, perm-pack lo)
__device__ inline ASplit splitA_fast(f32x8 v) {
    unsigned h[4], l[4];
    #pragma unroll
    for (int q = 0; q < 4; ++q) {
        unsigned u0 = __float_as_uint(v[2*q]);
        unsigned u1 = __float_as_uint(v[2*q+1]);
        h[q] = __builtin_amdgcn_perm(u1, u0, 0x07060302u);   // hi16(u0) | hi16(u1)<<16
        float r0 = v[2*q]   - __uint_as_float(u0 & 0xFFFF0000u);
        float r1 = v[2*q+1] - __uint_as_float(u1 & 0xFFFF0000u);
        l[q] = __builtin_amdgcn_perm(__float_as_uint(r1), __float_as_uint(r0), 0x07060302u);
    }
    ASplit r;
    r.h = __builtin_bit_cast(short8, *(uint4*)h);
    r.l = __builtin_bit_cast(short8, *(uint4*)l);
    return r;
}

__device__ inline f32x8 loadA8(const float* __restrict__ x, int i0) {
    f32x8 r;
    if (i0 >= 0 && i0 <= 15992) {
        float4 a0 = *(const float4*)(x + i0);
        float4 a1 = *(const float4*)(x + i0 + 4);
        r[0] = a0.x; r[1] = a0.y; r[2] = a0.z; r[3] = a0.w;
        r[4] = a1.x; r[5] = a1.y; r[6] = a1.z; r[7] = a1.w;
    } else {
        #pragma unroll
        for (int e = 0; e < 8; ++e) {
            int p = i0 + e;
            p = (p < 0) ? -p : p;
            p = (p > 15999) ? (31998 - p) : p;
            r[e] = x[p];
        }
    }
    return r;
}

__device__ inline void filter_params(int c, const float* low_hz_, const float* band_hz_,
                                     float* fctr, float* finv, int* fks, int* fke) {
    float lo = 50.0f + fabsf(low_hz_[c]);
    float hi = lo + 50.0f + fabsf(band_hz_[c]);
    hi = fminf(fmaxf(hi, 50.0f), 8000.0f);
    float ctr = 0.5f * (lo + hi);
    float hbw = 0.5f * (hi - lo);
    int ks = (int)ceilf(lo * 0.025f);
    if (ks < 0) ks = 0;
    while (40.0f * (float)ks < lo) ++ks;
    while (ks > 0 && 40.0f * (float)(ks - 1) >= lo) --ks;
    int ke = (int)floorf(hi * 0.025f);
    if (ke > 200) ke = 200;
    while (40.0f * (float)ke > hi) --ke;
    while (ke < 200 && 40.0f * (float)(ke + 1) <= hi) ++ke;
    fctr[c] = ctr;
    finv[c] = (hbw > 0.0f) ? (1.0f / hbw) : 0.0f;
    fks[c]  = ks;
    fke[c]  = ke;
}

// ---------------------------------------------------------------------------
// Kernel 1: filters output (64 x 201) -> tail of d_out.
// ---------------------------------------------------------------------------
__global__ void fse_filters(const float* __restrict__ low_hz_,
                            const float* __restrict__ band_hz_,
                            float* __restrict__ out)
{
    int idx = blockIdx.x * 256 + threadIdx.x;
    if (idx >= 64 * 201) return;
    int c = idx / 201;
    int k = idx - c * 201;
    float lo = 50.0f + fabsf(low_hz_[c]);
    float hi = lo + 50.0f + fabsf(band_hz_[c]);
    hi = fminf(fmaxf(hi, 50.0f), 8000.0f);
    float ctr = 0.5f * (lo + hi);
    float hbw = 0.5f * (hi - lo);
    float fq = 40.0f * (float)k;
    float resp = 1.0f - fabsf(fq - ctr) / hbw;
    out[idx] = (fq >= lo && fq <= hi) ? resp : 0.0f;
}

// ---------------------------------------------------------------------------
// Kernel 1b-16: B for BK=16: Bt[kc26][pl][g][row448][8] bf16 (hi/lo planes).
//   row j: j<=200 -> re bin j ; 224<=j<=424 -> im bin j-224 ; else 0.
//   n = kc*16 + g*8 + e. Chunk (one kc) = 14336 shorts = 28672 B.
// ---------------------------------------------------------------------------
__global__ void fse_setup_B16(unsigned short* __restrict__ bt)
{
    int idx = blockIdx.x * 256 + threadIdx.x;   // 26*2*2*448*8 = 372736
    if (idx >= 372736) return;
    int e   = idx & 7;
    int t   = idx >> 3;
    int row = t % 448;
    int q   = t / 448;          // ((kc*2 + pl)*2 + g)
    int g   = q & 1;
    int pl  = (q >> 1) & 1;
    int kc  = q >> 2;
    int n   = kc * 16 + g * 8 + e;
    float v = 0.0f;
    if (n < 400) {
        int bin = -1, isim = 0;
        if (row <= 200) bin = row;
        else if (row >= 224 && row <= 424) { bin = row - 224; isim = 1; }
        if (bin >= 0) {
            int a = (bin * n) % 400;
            float th = 6.283185307179586f * ((float)a / 400.0f);
            float sn, cs;
            sincosf(th, &sn, &cs);
            float wn = 0.5f - 0.5f * cosf(6.283185307179586f * ((float)n / 400.0f));
            v = isim ? (-wn * sn) : (wn * cs);
        }
    }
    unsigned short h = f2bf(v);
    float hf = __uint_as_float((unsigned)h << 16);
    unsigned short l = f2bf(v - hf);
    bt[idx] = pl ? l : h;
}

// ---------------------------------------------------------------------------
// Kernel 1b-32: B for BK=32 (fused fallback): Bt[kc13][pl][part4][row][8].
// ---------------------------------------------------------------------------
__global__ void fse_setup_B32(unsigned short* __restrict__ bt)
{
    int idx = blockIdx.x * 256 + threadIdx.x;   // 13*2*4*448*8 = 372736
    if (idx >= 372736) return;
    int e   = idx & 7;
    int t   = idx >> 3;
    int row = t % 448;
    int q   = t / 448;
    int p   = q & 3;
    int pl  = (q >> 2) & 1;
    int kc  = q >> 3;
    int n   = kc * 32 + p * 8 + e;
    float v = 0.0f;
    if (n < 400) {
        int bin = -1, isim = 0;
        if (row <= 200) bin = row;
        else if (row >= 224 && row <= 424) { bin = row - 224; isim = 1; }
        if (bin >= 0) {
            int a = (bin * n) % 400;
            float th = 6.283185307179586f * ((float)a / 400.0f);
            float sn, cs;
            sincosf(th, &sn, &cs);
            float wn = 0.5f - 0.5f * cosf(6.283185307179586f * ((float)n / 400.0f));
            v = isim ? (-wn * sn) : (wn * cs);
        }
    }
    unsigned short h = f2bf(v);
    float hf = __uint_as_float((unsigned)h << 16);
    unsigned short l = f2bf(v - hf);
    bt[idx] = pl ? l : h;
}

// ---------------------------------------------------------------------------
// Kernel A: 2 blocks per batch item (64 output rows each), BK=16,
//  double-buffered DMA (28.7KB x2), 1 barrier/kc, A one-kc-ahead in regs,
//  truncation split (perm-pack). 2 blocks/CU x 8 waves = 16 waves/CU.
//  Wave = (mt = w>>2, pq = w&3); pq owns (re,im) tile pairs {0,1}..{6}.
//  C layout (HW-verified m74): col = lane&31, row = (r&3)+8*(r>>2)+4*(lane>>5).
// ---------------------------------------------------------------------------
__global__ __launch_bounds__(512, 4)
void fse_gemm(const float* __restrict__ wav,
              const float* __restrict__ low_hz_,
              const float* __restrict__ band_hz_,
              const unsigned short* __restrict__ Bt,
              float* __restrict__ filt)
{
    __shared__ __align__(16) char smem[57344];   // 2 x 28672 B chunks | mags overlay
    __shared__ float fctr[64], finv[64];
    __shared__ int   fks[64], fke[64];
    float* mags = (float*)smem;                  // [64][201] f32 = 51456 B (post)

    const int bid  = blockIdx.x;
    const int b    = bid >> 1;
    const int half = bid & 1;
    const int tid  = threadIdx.x;
    const int w    = tid >> 6;
    const int lane = tid & 63;
    const float* __restrict__ x = wav + b * 16000;

    if (tid < 64) filter_params(tid, low_hz_, band_hz_, fctr, finv, fks, fke);

    const int mt    = w >> 2;
    const int pq    = w & 3;
    const int pbase = pq * 2;
    const int cnt   = (pq < 3) ? 2 : 1;
    const int jrow  = lane & 31;
    const int g     = lane >> 5;

    const int arow = 64 * half + 32 * mt + jrow;
    const int te   = (arow <= 100) ? arow : 50;
    const int ab   = 160 * te - 200 + g * 8;     // + kc*16

    const uint4* __restrict__ btg = (const uint4*)Bt;   // 1792 uint4 per kc-chunk

    // ---- prologue: A(0) into regs; DMA chunk 0 into buf0
    f32x8 aC = loadA8(x, ab);
    {
        #pragma unroll
        for (int i = 0; i < 4; ++i) {
            int idx = i * 512 + tid;
            if (idx < 1792) {   // wave-uniform guard (i=3 -> waves 0-3)
                __builtin_amdgcn_global_load_lds(
                    (const __attribute__((address_space(1))) unsigned*)(btg + idx),
                    (__attribute__((address_space(3))) unsigned*)(smem + idx * 16),
                    16, 0, 0);
            }
        }
    }
    __syncthreads();

    f32x16 accR[2], accI[2];
    #pragma unroll
    for (int i = 0; i < 2; ++i)
        #pragma unroll
        for (int e = 0; e < 16; ++e) { accR[i][e] = 0.0f; accI[i][e] = 0.0f; }

    int cur = 0;
    for (int kc = 0; kc < 26; ++kc) {
        const bool pre = (kc < 25);
        f32x8 aN;
        if (pre) {
            // DMA next chunk into the other buffer (its reads happen after
            // the barrier below); A(kc+1) into regs, consumed next iter.
            const uint4* src = btg + (kc + 1) * 1792;
            const int bufo = cur ^ 28672;
            #pragma unroll
            for (int i = 0; i < 4; ++i) {
                int idx = i * 512 + tid;
                if (idx < 1792) {
                    __builtin_amdgcn_global_load_lds(
                        (const __attribute__((address_space(1))) unsigned*)(src + idx),
                        (__attribute__((address_space(3))) unsigned*)(smem + bufo + idx * 16),
                        16, 0, 0);
                }
            }
            aN = loadA8(x, ab + (kc + 1) * 16);
        }

        ASplit S = splitA_fast(aC);

        const unsigned short* bs = (const unsigned short*)(smem + cur);
        #pragma unroll
        for (int i = 0; i < 2; ++i) {
            if (i < cnt) {
                const int p = pbase + i;
                const int roR = p * 32 + jrow;
                const int roI = (p + 7) * 32 + jrow;
                // layout within chunk: [pl][g][row][8] shorts
                short8 BhR = *(const short8*)(bs + ((0 + g) * 448 + roR) * 8);
                short8 BlR = *(const short8*)(bs + ((2 + g) * 448 + roR) * 8);
                short8 BhI = *(const short8*)(bs + ((0 + g) * 448 + roI) * 8);
                short8 BlI = *(const short8*)(bs + ((2 + g) * 448 + roI) * 8);
                accR[i] = __builtin_amdgcn_mfma_f32_32x32x16_bf16(S.h, BhR, accR[i], 0, 0, 0);
                accR[i] = __builtin_amdgcn_mfma_f32_32x32x16_bf16(S.h, BlR, accR[i], 0, 0, 0);
                accR[i] = __builtin_amdgcn_mfma_f32_32x32x16_bf16(S.l, BhR, accR[i], 0, 0, 0);
                accI[i] = __builtin_amdgcn_mfma_f32_32x32x16_bf16(S.h, BhI, accI[i], 0, 0, 0);
                accI[i] = __builtin_amdgcn_mfma_f32_32x32x16_bf16(S.h, BlI, accI[i], 0, 0, 0);
                accI[i] = __builtin_amdgcn_mfma_f32_32x32x16_bf16(S.l, BhI, accI[i], 0, 0, 0);
            }
        }

        __syncthreads();    // drains vmcnt: next chunk + aN complete; reads done
        if (pre) aC = aN;
        cur ^= 28672;
    }

    // ---- magnitude in-register, single LDS write pass (t local to half)
    #pragma unroll
    for (int i = 0; i < 2; ++i) {
        if (i < cnt) {
            const int k = (pbase + i) * 32 + jrow;
            if (k <= 200) {
                #pragma unroll
                for (int r = 0; r < 16; ++r) {
                    int tl = 32 * mt + (r & 3) + 8 * (r >> 2) + 4 * g;
                    float re = accR[i][r];
                    float im = accI[i][r];
                    mags[tl * 201 + k] = sqrtf(re * re + im * im);
                }
            }
        }
    }
    __syncthreads();

    // ---- filterbank: lane = t_local, wave-uniform k-loop
    const int tg = 64 * half + lane;
    #pragma unroll
    for (int i = 0; i < 8; ++i) {
        const int c = w * 8 + i;
        const float ctr = fctr[c];
        const float inv = finv[c];
        const int ks = fks[c], ke = fke[c];
        float a = 0.0f;
        for (int k = ks; k <= ke; ++k) {
            float resp = 1.0f - fabsf(40.0f * (float)k - ctr) * inv;
            a = fmaf(resp, mags[lane * 201 + k], a);
        }
        if (tg <= 100) filt[b * 6464 + c * 101 + tg] = a;
    }
}

// ---------------------------------------------------------------------------
// Kernel B: per batch item, LN + log10 + interp + store.
// ---------------------------------------------------------------------------
__global__ __launch_bounds__(256)
void fse_post(const float* __restrict__ filt,
              const float* __restrict__ ln_w,
              const float* __restrict__ ln_b,
              float* __restrict__ out)
{
    __shared__ float fbuf[6464];
    __shared__ float red[8];
    __shared__ float stats[2];
    const int b    = blockIdx.x;
    const int tid  = threadIdx.x;
    const int w    = tid >> 6;
    const int lane = tid & 63;
    const float* __restrict__ src = filt + b * 6464;

    float s = 0.0f, ss = 0.0f;
    for (int i = tid; i < 6464; i += 256) {
        float v = src[i];
        fbuf[i] = v;
        s += v;
        ss = fmaf(v, v, ss);
    }
    #pragma unroll
    for (int off = 32; off > 0; off >>= 1) {
        s  += __shfl_down(s,  off, 64);
        ss += __shfl_down(ss, off, 64);
    }
    if (lane == 0) { red[w] = s; red[4 + w] = ss; }
    __syncthreads();
    if (tid == 0) {
        float ts = 0.0f, tss = 0.0f;
        for (int i = 0; i < 4; ++i) { ts += red[i]; tss += red[4 + i]; }
        float mu = ts * (1.0f / 6464.0f);
        stats[0] = mu;
        stats[1] = tss * (1.0f / 6464.0f) - mu * mu;
    }
    __syncthreads();
    const float mu   = stats[0];
    const float isig = 1.0f / sqrtf(stats[1] + 1e-5f);

    for (int idx = tid; idx < 4096; idx += 256) {
        const int to = idx >> 6;
        const int c  = idx & 63;
        float pos = ((float)to + 0.5f) * 1.578125f - 0.5f;
        pos = fminf(fmaxf(pos, 0.0f), 100.0f);
        int i0 = (int)floorf(pos);
        int i1 = i0 + 1; if (i1 > 100) i1 = 100;
        float fr = pos - (float)i0;
        float wc = ln_w[c], bc = ln_b[c];
        float x0 = fbuf[c * 101 + i0];
        float x1 = fbuf[c * 101 + i1];
        float y0 = fmaf(wc, (x0 - mu) * isig, bc);
        float y1 = fmaf(wc, (x1 - mu) * isig, bc);
        float l0 = log10f(fmaf(y0, y0, 1e-6f));
        float l1 = log10f(fmaf(y1, y1, 1e-6f));
        out[b * 4096 + idx] = l0 * (1.0f - fr) + l1 * fr;
    }
}

// ---------------------------------------------------------------------------
// Fallback: R6 fused kernel (232 us) with BK=32 layout, if ws too small.
// ---------------------------------------------------------------------------
#define MSTR 209
__global__ __launch_bounds__(512, 2)
void fse_main_fused(const float* __restrict__ wav,
                    const float* __restrict__ low_hz_,
                    const float* __restrict__ band_hz_,
                    const float* __restrict__ ln_w,
                    const float* __restrict__ ln_b,
                    const unsigned short* __restrict__ Bt,
                    float* __restrict__ out)
{
    __shared__ __align__(16) char smem[114688];
    float* mags = (float*)smem;
    float* fbuf = (float*)(smem + 84544);
    __shared__ float fctr[64], finv[64];
    __shared__ int   fks[64], fke[64];
    __shared__ float red[16];
    __shared__ float stats[2];

    const int b    = blockIdx.x;
    const int tid  = threadIdx.x;
    const int w    = tid >> 6;
    const int lane = tid & 63;
    const float* __restrict__ x = wav + b * 16000;

    if (tid < 64) filter_params(tid, low_hz_, band_hz_, fctr, finv, fks, fke);

    const int mt   = w >> 1;
    const int half = w & 1;
    const int jrow = lane & 31;
    const int g    = lane >> 5;
    const int arow = mt * 32 + jrow;
    const int te   = (arow <= 100) ? arow : 50;
    const int abase = 160 * te - 200 + g * 8;

    const uint4* __restrict__ btg = (const uint4*)Bt;

    f32x8 ac0 = loadA8(x, abase);
    f32x8 ac1 = loadA8(x, abase + 16);
    {
        uint4 rr0 = btg[0 * 512 + tid], rr1 = btg[1 * 512 + tid];
        uint4 rr2 = btg[2 * 512 + tid], rr3 = btg[3 * 512 + tid];
        uint4 rr4 = btg[4 * 512 + tid], rr5 = btg[5 * 512 + tid];
        uint4 rr6 = btg[6 * 512 + tid];
        uint4* dst = (uint4*)smem;
        dst[0 * 512 + tid] = rr0; dst[1 * 512 + tid] = rr1;
        dst[2 * 512 + tid] = rr2; dst[3 * 512 + tid] = rr3;
        dst[4 * 512 + tid] = rr4; dst[5 * 512 + tid] = rr5;
        dst[6 * 512 + tid] = rr6;
    }
    __syncthreads();

    f32x16 acc[7];
    #pragma unroll
    for (int n = 0; n < 7; ++n)
        #pragma unroll
        for (int e = 0; e < 16; ++e) acc[n][e] = 0.0f;

    int curoff = 0;
    for (int kc = 0; kc < 13; ++kc) {
        const bool pre = (kc < 12);
        uint4 rr0, rr1, rr2, rr3, rr4, rr5, rr6;
        f32x8 an0, an1;
        if (pre) {
            const uint4* src = btg + (kc + 1) * 3584;
            rr0 = src[0 * 512 + tid]; rr1 = src[1 * 512 + tid];
            rr2 = src[2 * 512 + tid]; rr3 = src[3 * 512 + tid];
            rr4 = src[4 * 512 + tid]; rr5 = src[5 * 512 + tid];
            rr6 = src[6 * 512 + tid];
            an0 = loadA8(x, abase + (kc + 1) * 32);
            an1 = loadA8(x, abase + (kc + 1) * 32 + 16);
        }
        ASplit A0 = splitA(ac0);
        ASplit A1 = splitA(ac1);

        const unsigned short* bs = (const unsigned short*)(smem + curoff);
        #pragma unroll
        for (int s = 0; s < 2; ++s) {
            const short8 Ah = s ? A1.h : A0.h;
            const short8 Al = s ? A1.l : A0.l;
            const int pb = (s * 2 + g) * 448;
            #pragma unroll
            for (int n = 0; n < 7; ++n) {
                const int ro = (half * 7 + n) * 32 + jrow;
                short8 Bh = *(const short8*)(bs + (pb + ro) * 8);
                short8 Bl = *(const short8*)(bs + 14336 + (pb + ro) * 8);
                acc[n] = __builtin_amdgcn_mfma_f32_32x32x16_bf16(Ah, Bh, acc[n], 0, 0, 0);
                acc[n] = __builtin_amdgcn_mfma_f32_32x32x16_bf16(Ah, Bl, acc[n], 0, 0, 0);
                acc[n] = __builtin_amdgcn_mfma_f32_32x32x16_bf16(Al, Bh, acc[n], 0, 0, 0);
            }
        }
        if (pre) {
            uint4* dst = (uint4*)(smem + (curoff ^ 57344));
            dst[0 * 512 + tid] = rr0; dst[1 * 512 + tid] = rr1;
            dst[2 * 512 + tid] = rr2; dst[3 * 512 + tid] = rr3;
            dst[4 * 512 + tid] = rr4; dst[5 * 512 + tid] = rr5;
            dst[6 * 512 + tid] = rr6;
        }
        __syncthreads();
        if (pre) { ac0 = an0; ac1 = an1; }
        curoff ^= 57344;
    }

    if (half == 0) {
        #pragma unroll
        for (int n = 0; n < 7; ++n) {
            int k = n * 32 + jrow;
            if (k <= 200) {
                #pragma unroll
                for (int r = 0; r < 16; ++r) {
                    int t = mt * 32 + (r & 3) + 8 * (r >> 2) + 4 * g;
                    if (t <= 100) mags[t * MSTR + k] = acc[n][r];
                }
            }
        }
    }
    __syncthreads();
    if (half == 1) {
        #pragma unroll
        for (int n = 0; n < 7; ++n) {
            int k = n * 32 + jrow;
            if (k <= 200) {
                #pragma unroll
                for (int r = 0; r < 16; ++r) {
                    int t = mt * 32 + (r & 3) + 8 * (r >> 2) + 4 * g;
                    if (t <= 100) {
                        float re = mags[t * MSTR + k];
                        float im = acc[n][r];
                        mags[t * MSTR + k] = sqrtf(re * re + im * im);
                    }
                }
            }
        }
    }
    __syncthreads();

    {
        const int t0 = lane;
        const int t1v = 64 + lane;
        const int t1 = (t1v <= 100) ? t1v : 100;
        #pragma unroll
        for (int i = 0; i < 8; ++i) {
            const int c = w * 8 + i;
            const float ctr = fctr[c];
            const float inv = finv[c];
            const int ks = fks[c], ke = fke[c];
            float a0 = 0.0f, a1 = 0.0f;
            for (int k = ks; k <= ke; ++k) {
                float resp = 1.0f - fabsf(40.0f * (float)k - ctr) * inv;
                a0 = fmaf(resp, mags[t0 * MSTR + k], a0);
                a1 = fmaf(resp, mags[t1 * MSTR + k], a1);
            }
            fbuf[c * 101 + t0] = a0;
            if (t1v <= 100) fbuf[c * 101 + t1v] = a1;
        }
    }
    __syncthreads();

    float s = 0.0f, ss = 0.0f;
    for (int i = tid; i < 6464; i += 512) {
        float vv = fbuf[i];
        s += vv;
        ss = fmaf(vv, vv, ss);
    }
    #pragma unroll
    for (int off = 32; off > 0; off >>= 1) {
        s  += __shfl_down(s,  off, 64);
        ss += __shfl_down(ss, off, 64);
    }
    if (lane == 0) { red[w] = s; red[8 + w] = ss; }
    __syncthreads();
    if (tid == 0) {
        float ts = 0.0f, tss = 0.0f;
        for (int i = 0; i < 8; ++i) { ts += red[i]; tss += red[8 + i]; }
        float mu = ts * (1.0f / 6464.0f);
        stats[0] = mu;
        stats[1] = tss * (1.0f / 6464.0f) - mu * mu;
    }
    __syncthreads();
    const float mu   = stats[0];
    const float isig = 1.0f / sqrtf(stats[1] + 1e-5f);

    for (int idx = tid; idx < 4096; idx += 512) {
        const int to = idx >> 6;
        const int c  = idx & 63;
        float pos = ((float)to + 0.5f) * 1.578125f - 0.5f;
        pos = fminf(fmaxf(pos, 0.0f), 100.0f);
        int i0 = (int)floorf(pos);
        int i1 = i0 + 1; if (i1 > 100) i1 = 100;
        float fr = pos - (float)i0;
        float wc = ln_w[c], bc = ln_b[c];
        float x0 = fbuf[c * 101 + i0];
        float x1 = fbuf[c * 101 + i1];
        float y0 = fmaf(wc, (x0 - mu) * isig, bc);
        float y1 = fmaf(wc, (x1 - mu) * isig, bc);
        float l0 = log10f(fmaf(y0, y0, 1e-6f));
        float l1 = log10f(fmaf(y1, y1, 1e-6f));
        out[b * 4096 + idx] = l0 * (1.0f - fr) + l1 * fr;
    }
}

extern "C" void kernel_launch(void* const* d_in, const int* in_sizes, int n_in,
                              void* d_out, int out_size, void* d_ws, size_t ws_size,
                              hipStream_t stream)
{
    const float* wav = (const float*)d_in[0];
    const float* lo  = (const float*)d_in[1];
    const float* bd  = (const float*)d_in[2];
    const float* lw  = (const float*)d_in[3];
    const float* lb  = (const float*)d_in[4];
    float* out = (float*)d_out;

    fse_filters<<<(64 * 201 + 255) / 256, 256, 0, stream>>>(lo, bd, out + 1024 * 4096);

    const size_t BN1 = 745472;                                  // B table
    const size_t BN2 = BN1 + (size_t)1024 * 6464 * 4;           // + filtered
    unsigned short* Bts = (unsigned short*)d_ws;

    if (ws_size >= BN2) {
        float* filt = (float*)((char*)d_ws + BN1);
        fse_setup_B16<<<(372736 + 255) / 256, 256, 0, stream>>>(Bts);
        fse_gemm<<<2048, 512, 0, stream>>>(wav, lo, bd, Bts, filt);
        fse_post<<<1024, 256, 0, stream>>>(filt, lw, lb, out);
    } else {
        fse_setup_B32<<<(372736 + 255) / 256, 256, 0, stream>>>(Bts);
        fse_main_fused<<<1024, 512, 0, stream>>>(wav, lo, bd, lw, lb, Bts, out);
    }
}

// Round 12
// 219.490 us; speedup vs baseline: 1.3717x; 1.0151x over previous
//
#include <hip/hip_runtime.h>
#include <math.h>

#define BLOCK 1024
#define MSTR 209   // mags row stride (f32): odd -> conflict-free lane-major reads

typedef __attribute__((ext_vector_type(8))) short short8;
typedef __attribute__((ext_vector_type(16))) float f32x16;
typedef __attribute__((ext_vector_type(8))) float f32x8;

__device__ inline unsigned short f2bf(float x) {
    unsigned u = __float_as_uint(x);
    unsigned r = u + 0x7fffu + ((u >> 16) & 1u);
    return (unsigned short)(r >> 16);
}

struct ASplit { short8 h, l; };

// fast truncation split: 6 VALU per 2 values (perm-pack hi, sub, perm-pack lo)
__device__ inline ASplit splitA_fast(f32x8 v) {
    unsigned h[4], l[4];
    #pragma unroll
    for (int q = 0; q < 4; ++q) {
        unsigned u0 = __float_as_uint(v[2*q]);
        unsigned u1 = __float_as_uint(v[2*q+1]);
        h[q] = __builtin_amdgcn_perm(u1, u0, 0x07060302u);   // hi16(u0)|hi16(u1)<<16
        float r0 = v[2*q]   - __uint_as_float(u0 & 0xFFFF0000u);
        float r1 = v[2*q+1] - __uint_as_float(u1 & 0xFFFF0000u);
        l[q] = __builtin_amdgcn_perm(__float_as_uint(r1), __float_as_uint(r0), 0x07060302u);
    }
    ASplit r;
    r.h = __builtin_bit_cast(short8, *(uint4*)h);
    r.l = __builtin_bit_cast(short8, *(uint4*)l);
    return r;
}

__device__ inline f32x8 loadA8(const float* __restrict__ x, int i0) {
    f32x8 r;
    if (i0 >= 0 && i0 <= 15992) {
        float4 a0 = *(const float4*)(x + i0);
        float4 a1 = *(const float4*)(x + i0 + 4);
        r[0] = a0.x; r[1] = a0.y; r[2] = a0.z; r[3] = a0.w;
        r[4] = a1.x; r[5] = a1.y; r[6] = a1.z; r[7] = a1.w;
    } else {
        #pragma unroll
        for (int e = 0; e < 8; ++e) {
            int p = i0 + e;
            p = (p < 0) ? -p : p;
            p = (p > 15999) ? (31998 - p) : p;
            r[e] = x[p];
        }
    }
    return r;
}

__device__ inline void filter_params(int c, const float* low_hz_, const float* band_hz_,
                                     float* fctr, float* finv, int* fks, int* fke) {
    float lo = 50.0f + fabsf(low_hz_[c]);
    float hi = lo + 50.0f + fabsf(band_hz_[c]);
    hi = fminf(fmaxf(hi, 50.0f), 8000.0f);
    float ctr = 0.5f * (lo + hi);
    float hbw = 0.5f * (hi - lo);
    int ks = (int)ceilf(lo * 0.025f);
    if (ks < 0) ks = 0;
    while (40.0f * (float)ks < lo) ++ks;
    while (ks > 0 && 40.0f * (float)(ks - 1) >= lo) --ks;
    int ke = (int)floorf(hi * 0.025f);
    if (ke > 200) ke = 200;
    while (40.0f * (float)ke > hi) --ke;
    while (ke < 200 && 40.0f * (float)(ke + 1) <= hi) ++ke;
    fctr[c] = ctr;
    finv[c] = (hbw > 0.0f) ? (1.0f / hbw) : 0.0f;
    fks[c]  = ks;
    fke[c]  = ke;
}

// ---------------------------------------------------------------------------
// Kernel 1: filters output (64 x 201) -> tail of d_out.
// ---------------------------------------------------------------------------
__global__ void fse_filters(const float* __restrict__ low_hz_,
                            const float* __restrict__ band_hz_,
                            float* __restrict__ out)
{
    int idx = blockIdx.x * 256 + threadIdx.x;
    if (idx >= 64 * 201) return;
    int c = idx / 201;
    int k = idx - c * 201;
    float lo = 50.0f + fabsf(low_hz_[c]);
    float hi = lo + 50.0f + fabsf(band_hz_[c]);
    hi = fminf(fmaxf(hi, 50.0f), 8000.0f);
    float ctr = 0.5f * (lo + hi);
    float hbw = 0.5f * (hi - lo);
    float fq = 40.0f * (float)k;
    float resp = 1.0f - fabsf(fq - ctr) / hbw;
    out[idx] = (fq >= lo && fq <= hi) ? resp : 0.0f;
}

// ---------------------------------------------------------------------------
// Kernel 1b: B chunk-linear, BK=32: Bt[kc13][pl][part4][row448][8] bf16.
//   row j: j<=200 -> re bin j ; 224<=j<=424 -> im bin j-224 ; else 0.
// ---------------------------------------------------------------------------
__global__ void fse_setup_B(unsigned short* __restrict__ bt)
{
    int idx = blockIdx.x * 256 + threadIdx.x;   // 13*2*4*448*8 = 372736
    if (idx >= 372736) return;
    int e   = idx & 7;
    int t   = idx >> 3;
    int row = t % 448;
    int q   = t / 448;
    int p   = q & 3;
    int pl  = (q >> 2) & 1;
    int kc  = q >> 3;
    int n   = kc * 32 + p * 8 + e;
    float v = 0.0f;
    if (n < 400) {
        int bin = -1, isim = 0;
        if (row <= 200) bin = row;
        else if (row >= 224 && row <= 424) { bin = row - 224; isim = 1; }
        if (bin >= 0) {
            int a = (bin * n) % 400;
            float th = 6.283185307179586f * ((float)a / 400.0f);
            float sn, cs;
            sincosf(th, &sn, &cs);
            float wn = 0.5f - 0.5f * cosf(6.283185307179586f * ((float)n / 400.0f));
            v = isim ? (-wn * sn) : (wn * cs);
        }
    }
    unsigned short h = f2bf(v);
    float hf = __uint_as_float((unsigned)h << 16);
    unsigned short l = f2bf(v - hf);
    bt[idx] = pl ? l : h;
}

// ---------------------------------------------------------------------------
// Kernel 2: fully fused, ONE 1024-thread block per batch item.
//  16 waves = 4 mt (32-row tiles, M=128) x 4 pq (re/im bin-tile pairs).
//  BK=32, double-buffered DMA B (57.3KB x2), A one-kc-ahead in regs
//  (split-then-reload), fast truncation split, 1 barrier/kc (13 total).
//  acc = 64 regs/wave -> __launch_bounds__(1024,4): 4 waves/SIMD.
//  Post phase overlays the B buffers: mags[101][209] + fbuf[64*101].
//  C layout (HW-verified m74): col = lane&31, row = (r&3)+8*(r>>2)+4*(lane>>5).
// ---------------------------------------------------------------------------
__global__ __launch_bounds__(1024, 4)
void fse_main(const float* __restrict__ wav,
              const float* __restrict__ low_hz_,
              const float* __restrict__ band_hz_,
              const float* __restrict__ ln_w,
              const float* __restrict__ ln_b,
              const unsigned short* __restrict__ Bt,
              float* __restrict__ out)
{
    // GEMM: [0,57344) buf0 | [57344,114688) buf1
    // post: [0,84436) mags[101][209] | [84544,110400) fbuf[64*101]
    __shared__ __align__(16) char smem[114688];
    float* mags = (float*)smem;
    float* fbuf = (float*)(smem + 84544);

    __shared__ float fctr[64], finv[64];
    __shared__ int   fks[64], fke[64];
    __shared__ float red[32];
    __shared__ float stats[2];

    const int b    = blockIdx.x;
    const int tid  = threadIdx.x;
    const int w    = tid >> 6;          // 0..15
    const int lane = tid & 63;
    const float* __restrict__ x = wav + b * 16000;

    if (tid < 64) filter_params(tid, low_hz_, band_hz_, fctr, finv, fks, fke);

    const int mt    = w >> 2;           // 0..3 : rows 32*mt .. 32*mt+31
    const int pq    = w & 3;            // pair-group
    const int pbase = pq * 2;           // pairs {0,1},{2,3},{4,5},{6}
    const int cnt   = (pq < 3) ? 2 : 1;
    const int jrow  = lane & 31;
    const int g     = lane >> 5;

    const int arow = 32 * mt + jrow;
    const int te   = (arow <= 100) ? arow : 50;
    const int ab   = 160 * te - 200 + g * 8;     // + kc*32 + s*16

    const uint4* __restrict__ btg = (const uint4*)Bt;   // 3584 uint4 per chunk

    // ---- prologue: A(0) into regs; DMA chunk 0 into buf0
    f32x8 aC0 = loadA8(x, ab);
    f32x8 aC1 = loadA8(x, ab + 16);
    {
        #pragma unroll
        for (int i = 0; i < 4; ++i) {
            int idx = i * 1024 + tid;
            if (idx < 3584) {           // wave-uniform (i=3 -> waves 0-7)
                __builtin_amdgcn_global_load_lds(
                    (const __attribute__((address_space(1))) unsigned*)(btg + idx),
                    (__attribute__((address_space(3))) unsigned*)(smem + idx * 16),
                    16, 0, 0);
            }
        }
    }
    __syncthreads();

    f32x16 accR[2], accI[2];
    #pragma unroll
    for (int i = 0; i < 2; ++i)
        #pragma unroll
        for (int e = 0; e < 16; ++e) { accR[i][e] = 0.0f; accI[i][e] = 0.0f; }

    int cur = 0;
    for (int kc = 0; kc < 13; ++kc) {
        const bool pre = (kc < 12);

        // split current A first (frees aC regs), then issue next-kc loads
        ASplit S0 = splitA_fast(aC0);   // s=0
        ASplit S1 = splitA_fast(aC1);   // s=1

        if (pre) {
            const uint4* src = btg + (kc + 1) * 3584;
            const int bufo = cur ^ 57344;
            #pragma unroll
            for (int i = 0; i < 4; ++i) {
                int idx = i * 1024 + tid;
                if (idx < 3584) {
                    __builtin_amdgcn_global_load_lds(
                        (const __attribute__((address_space(1))) unsigned*)(src + idx),
                        (__attribute__((address_space(3))) unsigned*)(smem + bufo + idx * 16),
                        16, 0, 0);
                }
            }
            aC0 = loadA8(x, ab + (kc + 1) * 32);
            aC1 = loadA8(x, ab + (kc + 1) * 32 + 16);
        }

        const unsigned short* bs = (const unsigned short*)(smem + cur);
        #pragma unroll
        for (int s = 0; s < 2; ++s) {
            const short8 Ah = s ? S1.h : S0.h;
            const short8 Al = s ? S1.l : S0.l;
            const int part = s * 2 + g;
            const int bhof = part * 3584;          // [pl=0][part] base (shorts)
            const int blof = (4 + part) * 3584;    // [pl=1][part]
            #pragma unroll
            for (int i = 0; i < 2; ++i) {
                if (i < cnt) {
                    const int p = pbase + i;
                    const int roR = p * 32 + jrow;
                    const int roI = (p + 7) * 32 + jrow;
                    short8 BhR = *(const short8*)(bs + bhof + roR * 8);
                    short8 BlR = *(const short8*)(bs + blof + roR * 8);
                    short8 BhI = *(const short8*)(bs + bhof + roI * 8);
                    short8 BlI = *(const short8*)(bs + blof + roI * 8);
                    accR[i] = __builtin_amdgcn_mfma_f32_32x32x16_bf16(Ah, BhR, accR[i], 0, 0, 0);
                    accR[i] = __builtin_amdgcn_mfma_f32_32x32x16_bf16(Ah, BlR, accR[i], 0, 0, 0);
                    accR[i] = __builtin_amdgcn_mfma_f32_32x32x16_bf16(Al, BhR, accR[i], 0, 0, 0);
                    accI[i] = __builtin_amdgcn_mfma_f32_32x32x16_bf16(Ah, BhI, accI[i], 0, 0, 0);
                    accI[i] = __builtin_amdgcn_mfma_f32_32x32x16_bf16(Ah, BlI, accI[i], 0, 0, 0);
                    accI[i] = __builtin_amdgcn_mfma_f32_32x32x16_bf16(Al, BhI, accI[i], 0, 0, 0);
                }
            }
        }

        __syncthreads();    // drains vmcnt: next DMA + A complete; reads done
        cur ^= 57344;
    }

    // ---- magnitude fully in-register, single LDS write pass
    #pragma unroll
    for (int i = 0; i < 2; ++i) {
        if (i < cnt) {
            const int k = (pbase + i) * 32 + jrow;
            if (k <= 200) {
                #pragma unroll
                for (int r = 0; r < 16; ++r) {
                    int t = 32 * mt + (r & 3) + 8 * (r >> 2) + 4 * g;
                    if (t <= 100) {
                        float re = accR[i][r];
                        float im = accI[i][r];
                        mags[t * MSTR + k] = sqrtf(re * re + im * im);
                    }
                }
            }
        }
    }
    __syncthreads();

    // ---- filterbank: lane = t, 4 channels per wave, wave-uniform k-loop
    {
        const int t0 = lane;
        const int t1v = 64 + lane;
        const int t1 = (t1v <= 100) ? t1v : 100;
        #pragma unroll
        for (int i = 0; i < 4; ++i) {
            const int c = w * 4 + i;
            const float ctr = fctr[c];
            const float inv = finv[c];
            const int ks = fks[c], ke = fke[c];
            float a0 = 0.0f, a1 = 0.0f;
            for (int k = ks; k <= ke; ++k) {
                float resp = 1.0f - fabsf(40.0f * (float)k - ctr) * inv;
                a0 = fmaf(resp, mags[t0 * MSTR + k], a0);
                a1 = fmaf(resp, mags[t1 * MSTR + k], a1);
            }
            fbuf[c * 101 + t0] = a0;
            if (t1v <= 100) fbuf[c * 101 + t1v] = a1;
        }
    }
    __syncthreads();

    // ---- global LayerNorm (one-pass: sum + sumsq)
    float s = 0.0f, ss = 0.0f;
    for (int i = tid; i < 6464; i += BLOCK) {
        float vv = fbuf[i];
        s += vv;
        ss = fmaf(vv, vv, ss);
    }
    #pragma unroll
    for (int off = 32; off > 0; off >>= 1) {
        s  += __shfl_down(s,  off, 64);
        ss += __shfl_down(ss, off, 64);
    }
    if (lane == 0) { red[w] = s; red[16 + w] = ss; }
    __syncthreads();
    if (tid == 0) {
        float ts = 0.0f, tss = 0.0f;
        for (int i = 0; i < 16; ++i) { ts += red[i]; tss += red[16 + i]; }
        float mu = ts * (1.0f / 6464.0f);
        stats[0] = mu;
        stats[1] = tss * (1.0f / 6464.0f) - mu * mu;
    }
    __syncthreads();
    const float mu   = stats[0];
    const float isig = 1.0f / sqrtf(stats[1] + 1e-5f);

    // ---- log-energy + interp 101->64 + transposed store
    for (int idx = tid; idx < 4096; idx += BLOCK) {
        const int to = idx >> 6;
        const int c  = idx & 63;
        float pos = ((float)to + 0.5f) * 1.578125f - 0.5f;
        pos = fminf(fmaxf(pos, 0.0f), 100.0f);
        int i0 = (int)floorf(pos);
        int i1 = i0 + 1; if (i1 > 100) i1 = 100;
        float fr = pos - (float)i0;
        float wc = ln_w[c], bc = ln_b[c];
        float x0 = fbuf[c * 101 + i0];
        float x1 = fbuf[c * 101 + i1];
        float y0 = fmaf(wc, (x0 - mu) * isig, bc);
        float y1 = fmaf(wc, (x1 - mu) * isig, bc);
        float l0 = log10f(fmaf(y0, y0, 1e-6f));
        float l1 = log10f(fmaf(y1, y1, 1e-6f));
        out[b * 4096 + idx] = l0 * (1.0f - fr) + l1 * fr;
    }
}

extern "C" void kernel_launch(void* const* d_in, const int* in_sizes, int n_in,
                              void* d_out, int out_size, void* d_ws, size_t ws_size,
                              hipStream_t stream)
{
    const float* wav = (const float*)d_in[0];
    const float* lo  = (const float*)d_in[1];
    const float* bd  = (const float*)d_in[2];
    const float* lw  = (const float*)d_in[3];
    const float* lb  = (const float*)d_in[4];
    float* out = (float*)d_out;

    fse_filters<<<(64 * 201 + 255) / 256, 256, 0, stream>>>(lo, bd, out + 1024 * 4096);

    // ws_size has been >= 27MB every round; we need only 745472 B for B.
    unsigned short* Bts = (unsigned short*)d_ws;
    fse_setup_B<<<(372736 + 255) / 256, 256, 0, stream>>>(Bts);
    fse_main<<<1024, BLOCK, 0, stream>>>(wav, lo, bd, lw, lb, Bts, out);
}

// Round 13
// 213.921 us; speedup vs baseline: 1.4074x; 1.0260x over previous
//
#include <hip/hip_runtime.h>
#include <math.h>

#define BLOCK 1024
#define MSTR 209   // mags row stride (f32): odd -> conflict-free lane-major reads

typedef __attribute__((ext_vector_type(8))) short short8;
typedef __attribute__((ext_vector_type(16))) float f32x16;
typedef __attribute__((ext_vector_type(8))) float f32x8;

__device__ inline unsigned short f2bf(float x) {
    unsigned u = __float_as_uint(x);
    unsigned r = u + 0x7fffu + ((u >> 16) & 1u);
    return (unsigned short)(r >> 16);
}

struct ASplit { short8 h, l; };

// fast truncation split: 6 VALU per 2 values (perm-pack hi, sub, perm-pack lo)
__device__ inline ASplit splitA_fast(f32x8 v) {
    unsigned h[4], l[4];
    #pragma unroll
    for (int q = 0; q < 4; ++q) {
        unsigned u0 = __float_as_uint(v[2*q]);
        unsigned u1 = __float_as_uint(v[2*q+1]);
        h[q] = __builtin_amdgcn_perm(u1, u0, 0x07060302u);   // hi16(u0)|hi16(u1)<<16
        float r0 = v[2*q]   - __uint_as_float(u0 & 0xFFFF0000u);
        float r1 = v[2*q+1] - __uint_as_float(u1 & 0xFFFF0000u);
        l[q] = __builtin_amdgcn_perm(__float_as_uint(r1), __float_as_uint(r0), 0x07060302u);
    }
    ASplit r;
    r.h = __builtin_bit_cast(short8, *(uint4*)h);
    r.l = __builtin_bit_cast(short8, *(uint4*)l);
    return r;
}

__device__ inline f32x8 loadA8(const float* __restrict__ x, int i0) {
    f32x8 r;
    if (i0 >= 0 && i0 <= 15992) {
        float4 a0 = *(const float4*)(x + i0);
        float4 a1 = *(const float4*)(x + i0 + 4);
        r[0] = a0.x; r[1] = a0.y; r[2] = a0.z; r[3] = a0.w;
        r[4] = a1.x; r[5] = a1.y; r[6] = a1.z; r[7] = a1.w;
    } else {
        #pragma unroll
        for (int e = 0; e < 8; ++e) {
            int p = i0 + e;
            p = (p < 0) ? -p : p;
            p = (p > 15999) ? (31998 - p) : p;
            r[e] = x[p];
        }
    }
    return r;
}

__device__ inline void filter_params(int c, const float* low_hz_, const float* band_hz_,
                                     float* fctr, float* finv, int* fks, int* fke) {
    float lo = 50.0f + fabsf(low_hz_[c]);
    float hi = lo + 50.0f + fabsf(band_hz_[c]);
    hi = fminf(fmaxf(hi, 50.0f), 8000.0f);
    float ctr = 0.5f * (lo + hi);
    float hbw = 0.5f * (hi - lo);
    int ks = (int)ceilf(lo * 0.025f);
    if (ks < 0) ks = 0;
    while (40.0f * (float)ks < lo) ++ks;
    while (ks > 0 && 40.0f * (float)(ks - 1) >= lo) --ks;
    int ke = (int)floorf(hi * 0.025f);
    if (ke > 200) ke = 200;
    while (40.0f * (float)ke > hi) --ke;
    while (ke < 200 && 40.0f * (float)(ke + 1) <= hi) ++ke;
    fctr[c] = ctr;
    finv[c] = (hbw > 0.0f) ? (1.0f / hbw) : 0.0f;
    fks[c]  = ks;
    fke[c]  = ke;
}

// ---------------------------------------------------------------------------
// Kernel 1: filters output (64 x 201) -> tail of d_out.
// ---------------------------------------------------------------------------
__global__ void fse_filters(const float* __restrict__ low_hz_,
                            const float* __restrict__ band_hz_,
                            float* __restrict__ out)
{
    int idx = blockIdx.x * 256 + threadIdx.x;
    if (idx >= 64 * 201) return;
    int c = idx / 201;
    int k = idx - c * 201;
    float lo = 50.0f + fabsf(low_hz_[c]);
    float hi = lo + 50.0f + fabsf(band_hz_[c]);
    hi = fminf(fmaxf(hi, 50.0f), 8000.0f);
    float ctr = 0.5f * (lo + hi);
    float hbw = 0.5f * (hi - lo);
    float fq = 40.0f * (float)k;
    float resp = 1.0f - fabsf(fq - ctr) / hbw;
    out[idx] = (fq >= lo && fq <= hi) ? resp : 0.0f;
}

// ---------------------------------------------------------------------------
// Kernel 1b: B chunk-linear, BK=32: Bt[kc13][pl][part4][row448][8] bf16.
//   row j: j<=200 -> re bin j ; 224<=j<=424 -> im bin j-224 ; else 0.
// ---------------------------------------------------------------------------
__global__ void fse_setup_B(unsigned short* __restrict__ bt)
{
    int idx = blockIdx.x * 256 + threadIdx.x;   // 13*2*4*448*8 = 372736
    if (idx >= 372736) return;
    int e   = idx & 7;
    int t   = idx >> 3;
    int row = t % 448;
    int q   = t / 448;
    int p   = q & 3;
    int pl  = (q >> 2) & 1;
    int kc  = q >> 3;
    int n   = kc * 32 + p * 8 + e;
    float v = 0.0f;
    if (n < 400) {
        int bin = -1, isim = 0;
        if (row <= 200) bin = row;
        else if (row >= 224 && row <= 424) { bin = row - 224; isim = 1; }
        if (bin >= 0) {
            int a = (bin * n) % 400;
            float th = 6.283185307179586f * ((float)a / 400.0f);
            float sn, cs;
            sincosf(th, &sn, &cs);
            float wn = 0.5f - 0.5f * cosf(6.283185307179586f * ((float)n / 400.0f));
            v = isim ? (-wn * sn) : (wn * cs);
        }
    }
    unsigned short h = f2bf(v);
    float hf = __uint_as_float((unsigned)h << 16);
    unsigned short l = f2bf(v - hf);
    bt[idx] = pl ? l : h;
}

// ---------------------------------------------------------------------------
// K-step macro (T4 discipline):
//   top: s_waitcnt vmcnt(0)  -- my DMA(kc)+A(kc), issued a full phase ago
//        s_barrier           -- everyone's chunk kc complete
//   issue A(kc+1) then DMA(kc+1) -> buf^1 (stay in flight across the
//   end-of-iter lgkm wait and the next top barrier)
//   split A(kc); MFMA on buf[cur]
//   end: s_waitcnt lgkmcnt(0) -- my LDS reads landed (WAR-safe vs next DMA)
// ---------------------------------------------------------------------------
#define KSTEP(KC, CUROFF, A0c, A1c, A0n, A1n, PRE)                            \
  {                                                                           \
    asm volatile("s_waitcnt vmcnt(0)" ::: "memory");                          \
    __builtin_amdgcn_s_barrier();                                             \
    __builtin_amdgcn_sched_barrier(0);                                        \
    if (PRE) {                                                                \
      A0n = loadA8(x, ab + ((KC) + 1) * 32);                                  \
      A1n = loadA8(x, ab + ((KC) + 1) * 32 + 16);                             \
      const uint4* _src = btg + ((KC) + 1) * 3584;                            \
      const int _bufo = (CUROFF) ^ 57344;                                     \
      _Pragma("unroll")                                                       \
      for (int _i = 0; _i < 4; ++_i) {                                        \
        int _idx = _i * 1024 + tid;                                           \
        if (_idx < 3584) {                                                    \
          __builtin_amdgcn_global_load_lds(                                   \
              (const __attribute__((address_space(1))) unsigned*)(_src + _idx), \
              (__attribute__((address_space(3))) unsigned*)(smem + _bufo + _idx * 16), \
              16, 0, 0);                                                      \
        }                                                                     \
      }                                                                       \
    }                                                                         \
    ASplit _S0 = splitA_fast(A0c);                                            \
    ASplit _S1 = splitA_fast(A1c);                                            \
    const unsigned short* _bs = (const unsigned short*)(smem + (CUROFF));     \
    _Pragma("unroll")                                                         \
    for (int _s = 0; _s < 2; ++_s) {                                          \
      const short8 _Ah = _s ? _S1.h : _S0.h;                                  \
      const short8 _Al = _s ? _S1.l : _S0.l;                                  \
      const int _part = _s * 2 + g;                                           \
      const int _bhof = _part * 3584;                                         \
      const int _blof = (4 + _part) * 3584;                                   \
      _Pragma("unroll")                                                       \
      for (int _i2 = 0; _i2 < 2; ++_i2) {                                     \
        if (_i2 < cnt) {                                                      \
          const int _p = pbase + _i2;                                         \
          const int _roR = _p * 32 + jrow;                                    \
          const int _roI = (_p + 7) * 32 + jrow;                              \
          short8 _BhR = *(const short8*)(_bs + _bhof + _roR * 8);             \
          short8 _BlR = *(const short8*)(_bs + _blof + _roR * 8);             \
          short8 _BhI = *(const short8*)(_bs + _bhof + _roI * 8);             \
          short8 _BlI = *(const short8*)(_bs + _blof + _roI * 8);             \
          accR[_i2] = __builtin_amdgcn_mfma_f32_32x32x16_bf16(_Ah, _BhR, accR[_i2], 0, 0, 0); \
          accR[_i2] = __builtin_amdgcn_mfma_f32_32x32x16_bf16(_Ah, _BlR, accR[_i2], 0, 0, 0); \
          accR[_i2] = __builtin_amdgcn_mfma_f32_32x32x16_bf16(_Al, _BhR, accR[_i2], 0, 0, 0); \
          accI[_i2] = __builtin_amdgcn_mfma_f32_32x32x16_bf16(_Ah, _BhI, accI[_i2], 0, 0, 0); \
          accI[_i2] = __builtin_amdgcn_mfma_f32_32x32x16_bf16(_Ah, _BlI, accI[_i2], 0, 0, 0); \
          accI[_i2] = __builtin_amdgcn_mfma_f32_32x32x16_bf16(_Al, _BhI, accI[_i2], 0, 0, 0); \
        }                                                                     \
      }                                                                       \
    }                                                                         \
    asm volatile("s_waitcnt lgkmcnt(0)" ::: "memory");                        \
    __builtin_amdgcn_sched_barrier(0);                                        \
  }

// ---------------------------------------------------------------------------
// Kernel 2: fully fused, ONE 1024-thread block per batch item.
//  16 waves = 4 mt x 4 pq (re/im bin-tile pairs). BK=32, dbuf DMA B,
//  A one-kc-ahead in two named register sets (no rollover copies),
//  counted-wait raw barriers (prefetch never drained mid-loop).
//  C layout (HW-verified m74): col = lane&31, row = (r&3)+8*(r>>2)+4*(lane>>5).
// ---------------------------------------------------------------------------
__global__ __launch_bounds__(1024, 4)
void fse_main(const float* __restrict__ wav,
              const float* __restrict__ low_hz_,
              const float* __restrict__ band_hz_,
              const float* __restrict__ ln_w,
              const float* __restrict__ ln_b,
              const unsigned short* __restrict__ Bt,
              float* __restrict__ out)
{
    // GEMM: [0,57344) buf0 | [57344,114688) buf1
    // post: [0,84436) mags[101][209] | [84544,110400) fbuf[64*101]
    __shared__ __align__(16) char smem[114688];
    float* mags = (float*)smem;
    float* fbuf = (float*)(smem + 84544);

    __shared__ float fctr[64], finv[64];
    __shared__ int   fks[64], fke[64];
    __shared__ float red[32];
    __shared__ float stats[2];

    const int b    = blockIdx.x;
    const int tid  = threadIdx.x;
    const int w    = tid >> 6;          // 0..15
    const int lane = tid & 63;
    const float* __restrict__ x = wav + b * 16000;

    if (tid < 64) filter_params(tid, low_hz_, band_hz_, fctr, finv, fks, fke);

    const int mt    = w >> 2;           // 0..3 : rows 32*mt .. 32*mt+31
    const int pq    = w & 3;            // pair-group
    const int pbase = pq * 2;           // pairs {0,1},{2,3},{4,5},{6}
    const int cnt   = (pq < 3) ? 2 : 1;
    const int jrow  = lane & 31;
    const int g     = lane >> 5;

    const int arow = 32 * mt + jrow;
    const int te   = (arow <= 100) ? arow : 50;
    const int ab   = 160 * te - 200 + g * 8;     // + kc*32 + s*16

    const uint4* __restrict__ btg = (const uint4*)Bt;   // 3584 uint4 per chunk

    // ---- prologue: A(0) into aE; DMA chunk 0 into buf0 (waited in KSTEP 0)
    f32x8 aE0 = loadA8(x, ab);
    f32x8 aE1 = loadA8(x, ab + 16);
    f32x8 aO0, aO1;
    {
        #pragma unroll
        for (int i = 0; i < 4; ++i) {
            int idx = i * 1024 + tid;
            if (idx < 3584) {
                __builtin_amdgcn_global_load_lds(
                    (const __attribute__((address_space(1))) unsigned*)(btg + idx),
                    (__attribute__((address_space(3))) unsigned*)(smem + idx * 16),
                    16, 0, 0);
            }
        }
    }

    f32x16 accR[2], accI[2];
    #pragma unroll
    for (int i = 0; i < 2; ++i)
        #pragma unroll
        for (int e = 0; e < 16; ++e) { accR[i][e] = 0.0f; accI[i][e] = 0.0f; }

    KSTEP(0,  0,     aE0, aE1, aO0, aO1, true)
    KSTEP(1,  57344, aO0, aO1, aE0, aE1, true)
    KSTEP(2,  0,     aE0, aE1, aO0, aO1, true)
    KSTEP(3,  57344, aO0, aO1, aE0, aE1, true)
    KSTEP(4,  0,     aE0, aE1, aO0, aO1, true)
    KSTEP(5,  57344, aO0, aO1, aE0, aE1, true)
    KSTEP(6,  0,     aE0, aE1, aO0, aO1, true)
    KSTEP(7,  57344, aO0, aO1, aE0, aE1, true)
    KSTEP(8,  0,     aE0, aE1, aO0, aO1, true)
    KSTEP(9,  57344, aO0, aO1, aE0, aE1, true)
    KSTEP(10, 0,     aE0, aE1, aO0, aO1, true)
    KSTEP(11, 57344, aO0, aO1, aE0, aE1, true)
    KSTEP(12, 0,     aE0, aE1, aO0, aO1, false)

    __syncthreads();   // GEMM done; smem reusable as mags/fbuf

    // ---- magnitude fully in-register, single LDS write pass
    #pragma unroll
    for (int i = 0; i < 2; ++i) {
        if (i < cnt) {
            const int k = (pbase + i) * 32 + jrow;
            if (k <= 200) {
                #pragma unroll
                for (int r = 0; r < 16; ++r) {
                    int t = 32 * mt + (r & 3) + 8 * (r >> 2) + 4 * g;
                    if (t <= 100) {
                        float re = accR[i][r];
                        float im = accI[i][r];
                        mags[t * MSTR + k] = sqrtf(re * re + im * im);
                    }
                }
            }
        }
    }
    __syncthreads();

    // ---- filterbank: lane = t, 4 channels per wave, wave-uniform k-loop
    {
        const int t0 = lane;
        const int t1v = 64 + lane;
        const int t1 = (t1v <= 100) ? t1v : 100;
        #pragma unroll
        for (int i = 0; i < 4; ++i) {
            const int c = w * 4 + i;
            const float ctr = fctr[c];
            const float inv = finv[c];
            const int ks = fks[c], ke = fke[c];
            float a0 = 0.0f, a1 = 0.0f;
            for (int k = ks; k <= ke; ++k) {
                float resp = 1.0f - fabsf(40.0f * (float)k - ctr) * inv;
                a0 = fmaf(resp, mags[t0 * MSTR + k], a0);
                a1 = fmaf(resp, mags[t1 * MSTR + k], a1);
            }
            fbuf[c * 101 + t0] = a0;
            if (t1v <= 100) fbuf[c * 101 + t1v] = a1;
        }
    }
    __syncthreads();

    // ---- global LayerNorm (one-pass: sum + sumsq)
    float s = 0.0f, ss = 0.0f;
    for (int i = tid; i < 6464; i += BLOCK) {
        float vv = fbuf[i];
        s += vv;
        ss = fmaf(vv, vv, ss);
    }
    #pragma unroll
    for (int off = 32; off > 0; off >>= 1) {
        s  += __shfl_down(s,  off, 64);
        ss += __shfl_down(ss, off, 64);
    }
    if (lane == 0) { red[w] = s; red[16 + w] = ss; }
    __syncthreads();
    if (tid == 0) {
        float ts = 0.0f, tss = 0.0f;
        for (int i = 0; i < 16; ++i) { ts += red[i]; tss += red[16 + i]; }
        float mu = ts * (1.0f / 6464.0f);
        stats[0] = mu;
        stats[1] = tss * (1.0f / 6464.0f) - mu * mu;
    }
    __syncthreads();
    const float mu   = stats[0];
    const float isig = 1.0f / sqrtf(stats[1] + 1e-5f);

    // ---- log-energy + interp 101->64 + transposed store
    for (int idx = tid; idx < 4096; idx += BLOCK) {
        const int to = idx >> 6;
        const int c  = idx & 63;
        float pos = ((float)to + 0.5f) * 1.578125f - 0.5f;
        pos = fminf(fmaxf(pos, 0.0f), 100.0f);
        int i0 = (int)floorf(pos);
        int i1 = i0 + 1; if (i1 > 100) i1 = 100;
        float fr = pos - (float)i0;
        float wc = ln_w[c], bc = ln_b[c];
        float x0 = fbuf[c * 101 + i0];
        float x1 = fbuf[c * 101 + i1];
        float y0 = fmaf(wc, (x0 - mu) * isig, bc);
        float y1 = fmaf(wc, (x1 - mu) * isig, bc);
        float l0 = log10f(fmaf(y0, y0, 1e-6f));
        float l1 = log10f(fmaf(y1, y1, 1e-6f));
        out[b * 4096 + idx] = l0 * (1.0f - fr) + l1 * fr;
    }
}

extern "C" void kernel_launch(void* const* d_in, const int* in_sizes, int n_in,
                              void* d_out, int out_size, void* d_ws, size_t ws_size,
                              hipStream_t stream)
{
    const float* wav = (const float*)d_in[0];
    const float* lo  = (const float*)d_in[1];
    const float* bd  = (const float*)d_in[2];
    const float* lw  = (const float*)d_in[3];
    const float* lb  = (const float*)d_in[4];
    float* out = (float*)d_out;

    fse_filters<<<(64 * 201 + 255) / 256, 256, 0, stream>>>(lo, bd, out + 1024 * 4096);

    unsigned short* Bts = (unsigned short*)d_ws;   // 745472 B needed; ws proven larger
    fse_setup_B<<<(372736 + 255) / 256, 256, 0, stream>>>(Bts);
    fse_main<<<1024, BLOCK, 0, stream>>>(wav, lo, bd, lw, lb, Bts, out);
}